// Round 4
// baseline (778.618 us; speedup 1.0000x reference)
//
#include <hip/hip_runtime.h>
#include <math.h>

// ---------------------------------------------------------------------------
// TemporalGCN: 2-layer LSTM (per-node sequences) -> 2 GCN rounds -> edge MLP.
//
// R12: R11 post-mortem: VGPR_Count=128 + 17MB WRITE_SIZE = the allocator
// (under launch_bounds(512,2)) spilled the 134 weight floats to scratch and
// re-fetched them every phase. The DS-reduction idea (1536->1024 b128/phase)
// was right; the register plan was wrong. New wave split that never exceeds
// 128 weight floats/thread and uses launch_bounds(512,1) (8-wave block
// already forces VGPR<=256; the ",2" hint is what invited the 128 cap):
//   waves 0-3: L0 gates, r=1 (verbatim R9 path; 64 wfloats; DS 512 b128/ph)
//   waves 4-5: xproj, r=2 rows/thread (Wih1 rows j, j+128; one h0 b128
//              feeds both rows) -> DS 256
//   waves 6-7: L1 dot, r=2 (Whh1 rows j, j+128; a0/b0 seeded from x1_sh
//              written one phase earlier, parity dbuf) -> DS 256
// Updates: L0 by tid<256, L1 by tid>=256, both verbatim R9 (w,u)->{w,w+4}.
// 14 phases, 2 barriers each. k_node/k_mlp reverted to the R9 (best-total)
// versions -- the R11 rewrites measured ~+11us in the R3 residual.
//
// Bit-exactness: per-output accumulation trees verbatim (quarter-split
// a0..a3 float4 dot, ascending-q fmaf chain, +bias1 before seeding,
// c = fv*c + iv*gv) -> absmax 0.0 preserved.
// ---------------------------------------------------------------------------

#define Hd   64
#define Ed   5
#define Fd   6
#define Bd   8
#define Wd   12
#define Nd   200
#define NSEQ (Bd*Nd)        // 1600 sequences (b,n)
#define NG   (4*Hd)         // 256 gate rows
#define SEQPB 8             // sequences per fused-LSTM block (200 % 8 == 0)
#define LNEPS 1e-5f

__device__ __forceinline__ float sigm(float x) { return 1.0f / (1.0f + __expf(-x)); }
__device__ __forceinline__ float tanh_fast(float x) {
  float ax = fabsf(x);
  float t  = __expf(-2.0f * ax);
  float r  = (1.0f - t) / (1.0f + t);
  return copysignf(r, x);
}

// --------------------------------------------------------------------------
// Prep: gcnWT[round][k][u]; epWT[round][e][u]; W1aT[k][n]=W1[n][k];
// W1bT[k][n]=W1[n][64+k]. Sizes: 8192 + 640 + 4096 + 4096 = 17024 elements.
__global__ __launch_bounds__(256) void k_prep(
    const float* __restrict__ gcn_W, const float* __restrict__ ep_W,
    const float* __restrict__ W1,
    float* __restrict__ gcnWT, float* __restrict__ epWT,
    float* __restrict__ W1aT, float* __restrict__ W1bT)
{
  int idx = blockIdx.x * 256 + threadIdx.x;
  if (idx < 8192) {                        // gcnWT[r][k][u] = gcn_W[r][u][k]
    int round = idx >> 12, rem = idx & 4095;
    int k = rem >> 6, u = rem & 63;
    gcnWT[idx] = gcn_W[round * 4096 + u * 64 + k];
  } else if (idx < 8832) {                 // epWT[r][e][u] = ep_W[r][u][e]
    int r0 = idx - 8192;
    int round = r0 / 320, rem = r0 % 320;
    int e = rem >> 6, u = rem & 63;
    epWT[r0] = ep_W[round * 320 + u * Ed + e];
  } else if (idx < 12928) {                // W1aT[k][n] = W1[n][k]
    int r0 = idx - 8832;
    int k = r0 >> 6, n = r0 & 63;
    W1aT[r0] = W1[n * 133 + k];
  } else if (idx < 17024) {                // W1bT[k][n] = W1[n][64+k]
    int r0 = idx - 12928;
    int k = r0 >> 6, n = r0 & 63;
    W1bT[r0] = W1[n * 133 + 64 + k];
  }
}

// --------------------------------------------------------------------------
// Fused 2-layer LSTM. 200 blocks x 512 threads, 8 seqs/block.
// Phase t in [0,13]:
//   waves 0-3: L0 gates step t (t<12), r=1            -- reads h0_sh
//   waves 4-5: xproj xv(t-1) (1<=t<=12), r=2          -- reads h0_sh
//   waves 6-7: L1 gates step t-2 (t>=2), r=2          -- reads h1_sh, x1_sh
// barrier; L0 update (tid<256), L1 update (tid>=256); barrier.
__global__ __launch_bounds__(512, 1) void k_lstm_fused(
    const float* __restrict__ nf,                       // (B,W,N,F)
    const float* __restrict__ Wih0, const float* __restrict__ Whh0,
    const float* __restrict__ bih0, const float* __restrict__ bhh0,
    const float* __restrict__ Wih1, const float* __restrict__ Whh1,
    const float* __restrict__ bih1, const float* __restrict__ bhh1,
    float* __restrict__ hout)                           // (NSEQ, H)
{
  __shared__ float x_sh[SEQPB][Wd * Fd];   // 576
  __shared__ float h0_sh[SEQPB][Hd];       // 512
  __shared__ float h1_sh[SEQPB][Hd];       // 512
  __shared__ float g0_sh[SEQPB][NG];       // 2048 (post-activation gates L0)
  __shared__ float g1_sh[SEQPB][NG];       // 2048 (post-activation gates L1)
  __shared__ float x1_sh[2][SEQPB][NG];    // 4096 (xv = Wih1.h0 + bias1)

  const int tid  = threadIdx.x;
  const int seq0 = blockIdx.x * SEQPB;
  const int b    = seq0 / Nd;              // uniform (200 % 8 == 0)
  const int n0   = seq0 % Nd;

  for (int idx = tid; idx < SEQPB * Wd * Fd; idx += 512) {
    int s = idx / (Wd * Fd), r = idx - s * (Wd * Fd);
    int t = r / Fd, f = r - t * Fd;
    x_sh[s][r] = nf[((b * Wd + t) * Nd + (n0 + s)) * Fd + f];
  }
  ((float*)h0_sh)[tid] = 0.f;              // 512 floats, one per thread
  ((float*)h1_sh)[tid] = 0.f;

  const int role = tid >> 7;               // 0,1 = L0; 2 = xproj; 3 = L1
  const int u    = tid & 63;
  const int w    = (tid >> 6) & 3;         // update ownership: seqs {w, w+4}

  // ---- per-role weights (registers) ----
  // L0 (tid<256): Whh0 row tid (64f) + Wih0 row (6f).
  float4 wh[16];  float wx[Fd];  float bias0 = 0.f;
  // xproj (role 2): Wih1 rows jx, jx+128 (128f).
  float4 wiA[16], wiB[16];  float biasA = 0.f, biasB = 0.f;
  // L1 (role 3): Whh1 rows jy, jy+128 (128f).  (aliases wiA/wiB? keep sep.)
  float4 whA[16], whB[16];
  const int jsub = tid & 127;              // row-lo for roles 2,3

  if (role < 2) {
    const int j = tid;
    const float4* wr = (const float4*)(Whh0 + j * Hd);
    #pragma unroll
    for (int q = 0; q < 16; ++q) wh[q] = wr[q];
    #pragma unroll
    for (int f = 0; f < Fd; ++f) wx[f] = Wih0[j * Fd + f];
    bias0 = bih0[j] + bhh0[j];
  } else if (role == 2) {
    const float4* ra = (const float4*)(Wih1 + jsub * Hd);
    const float4* rb = (const float4*)(Wih1 + (jsub + 128) * Hd);
    #pragma unroll
    for (int q = 0; q < 16; ++q) { wiA[q] = ra[q]; wiB[q] = rb[q]; }
    biasA = bih1[jsub] + bhh1[jsub];
    biasB = bih1[jsub + 128] + bhh1[jsub + 128];
  } else {
    const float4* ra = (const float4*)(Whh1 + jsub * Hd);
    const float4* rb = (const float4*)(Whh1 + (jsub + 128) * Hd);
    #pragma unroll
    for (int q = 0; q < 16; ++q) { whA[q] = ra[q]; whB[q] = rb[q]; }
  }

  float cA = 0.f, cB = 0.f;                // cell states for seqs w, w+4
  float hA = 0.f, hB = 0.f;                // tid>=256: final h1 for w, w+4
  __syncthreads();

  for (int t = 0; t <= Wd + 1; ++t) {
    // ================= gate section ======================================
    if (role < 2) {
      if (t < Wd) {                        // L0 gates step t (verbatim R9)
        const int j = tid, jt = j >> 6;
        #pragma unroll 2
        for (int s = 0; s < SEQPB; ++s) {
          const float* xp = &x_sh[s][t * Fd];
          float a0 = bias0, a1 = 0.f, a2 = 0.f, a3 = 0.f;
          #pragma unroll
          for (int f = 0; f < Fd; ++f) a1 += xp[f] * wx[f];
          const float4* h4 = (const float4*)h0_sh[s];
          #pragma unroll
          for (int q = 0; q < 16; ++q) {
            float4 hv = h4[q];
            float d = hv.x * wh[q].x + hv.y * wh[q].y + hv.z * wh[q].z + hv.w * wh[q].w;
            if ((q & 3) == 0) a0 += d; else if ((q & 3) == 1) a1 += d;
            else if ((q & 3) == 2) a2 += d; else a3 += d;
          }
          float acc = (a0 + a1) + (a2 + a3);
          g0_sh[s][j] = (jt == 2) ? tanh_fast(acc) : sigm(acc);
        }
      }
    } else if (role == 2) {
      if (t >= 1 && t <= Wd) {             // xv(t-1): one h0 b128, two rows
        #pragma unroll 2
        for (int s = 0; s < SEQPB; ++s) {
          const float4* h4 = (const float4*)h0_sh[s];
          float xa = 0.f, xb = 0.f;
          #pragma unroll
          for (int q = 0; q < 16; ++q) {
            float4 hv = h4[q];
            xa = fmaf(hv.x, wiA[q].x, xa);
            xa = fmaf(hv.y, wiA[q].y, xa);
            xa = fmaf(hv.z, wiA[q].z, xa);
            xa = fmaf(hv.w, wiA[q].w, xa);
            xb = fmaf(hv.x, wiB[q].x, xb);
            xb = fmaf(hv.y, wiB[q].y, xb);
            xb = fmaf(hv.z, wiB[q].z, xb);
            xb = fmaf(hv.w, wiB[q].w, xb);
          }
          x1_sh[t & 1][s][jsub]       = xa + biasA;
          x1_sh[t & 1][s][jsub + 128] = xb + biasB;
        }
      }
    } else {
      if (t >= 2) {                        // L1 gates step t-2: r=2
        const int jtA = jsub >> 6;         // 0 or 1 (i / f gate)
        const int jtB = 2 + (jsub >> 6);   // 2 or 3 (g / o gate)
        #pragma unroll 2
        for (int s = 0; s < SEQPB; ++s) {
          const float* xv = x1_sh[(t - 1) & 1][s];   // written phase t-1
          float a0 = xv[jsub],       a1 = 0.f, a2 = 0.f, a3 = 0.f;
          float e0 = xv[jsub + 128], e1 = 0.f, e2 = 0.f, e3 = 0.f;
          const float4* h4 = (const float4*)h1_sh[s];
          #pragma unroll
          for (int q = 0; q < 16; ++q) {
            float4 hv = h4[q];
            float dA = hv.x * whA[q].x + hv.y * whA[q].y + hv.z * whA[q].z + hv.w * whA[q].w;
            float dB = hv.x * whB[q].x + hv.y * whB[q].y + hv.z * whB[q].z + hv.w * whB[q].w;
            if ((q & 3) == 0) { a0 += dA; e0 += dB; }
            else if ((q & 3) == 1) { a1 += dA; e1 += dB; }
            else if ((q & 3) == 2) { a2 += dA; e2 += dB; }
            else { a3 += dA; e3 += dB; }
          }
          float accA = (a0 + a1) + (a2 + a3);
          float accB = (e0 + e1) + (e2 + e3);
          g1_sh[s][jsub]       = (jtA == 2) ? tanh_fast(accA) : sigm(accA);
          g1_sh[s][jsub + 128] = (jtB == 2) ? tanh_fast(accB) : sigm(accB);
        }
      }
    }
    __syncthreads();                       // gates/xv ready; h reads done

    // ================= update section (verbatim R9 ownership) ============
    if (tid < 256) {
      if (t < Wd) {                        // L0 update step t
        const float* gb = g0_sh[w];
        float iv = gb[u], fv = gb[64 + u], gv = gb[128 + u], ov = gb[192 + u];
        cA = fv * cA + iv * gv;
        hA = ov * tanh_fast(cA);
        h0_sh[w][u] = hA;
        const float* gb2 = g0_sh[w + 4];
        float iv2 = gb2[u], fv2 = gb2[64 + u], gv2 = gb2[128 + u], ov2 = gb2[192 + u];
        cB = fv2 * cB + iv2 * gv2;
        hB = ov2 * tanh_fast(cB);
        h0_sh[w + 4][u] = hB;
      }
    } else {
      if (t >= 2) {                        // L1 update step t-2
        const float* gb = g1_sh[w];
        float iv = gb[u], fv = gb[64 + u], gv = gb[128 + u], ov = gb[192 + u];
        cA = fv * cA + iv * gv;
        hA = ov * tanh_fast(cA);
        h1_sh[w][u] = hA;
        const float* gb2 = g1_sh[w + 4];
        float iv2 = gb2[u], fv2 = gb2[64 + u], gv2 = gb2[128 + u], ov2 = gb2[192 + u];
        cB = fv2 * cB + iv2 * gv2;
        hB = ov2 * tanh_fast(cB);
        h1_sh[w + 4][u] = hB;
      }
    }
    __syncthreads();                       // h writes visible to next phase
  }

  // Final h1(11) -> hout from L1 state owners (tid>=256). Coalesced.
  if (tid >= 256) {
    hout[(seq0 + w) * Hd + u]     = hA;
    hout[(seq0 + w + 4) * Hd + u] = hB;
  }
}

// --------------------------------------------------------------------------
// Fused per-row node pipeline: wsum -> GCN r0 -> GCN r1 -> u/v precompute.
// One block per row (b,i); 256 threads. adj/ef rows staged into LDS with
// COALESCED loads; all weight reads coalesced via the k_prep transposes.
// (R9 version -- the R11 wave-redundant rewrite measured slightly worse.)
__global__ __launch_bounds__(256) void k_node(
    const float* __restrict__ ef,    const float* __restrict__ adj,
    const float* __restrict__ h0,
    const float* __restrict__ gcnWT, const float* __restrict__ gcn_b,
    const float* __restrict__ epWT,  const float* __restrict__ ep_b,
    const float* __restrict__ ln_g,  const float* __restrict__ ln_b,
    const float* __restrict__ W1aT,  const float* __restrict__ W1bT,
    const float* __restrict__ b1,
    float* __restrict__ uu, float* __restrict__ vt)
{
  __shared__ float ef_sh[Nd * Ed];   // 1000: edge_last row (coalesced stage)
  __shared__ float adj_sh[Nd];       // 200
  __shared__ float red[4][6];
  __shared__ float w6[6];
  __shared__ float hcur[Hd];

  const int row = blockIdx.x;      // b*200+i
  const int b = row / Nd, i = row % Nd;
  const int tid = threadIdx.x;

  const float* efrow = ef + (size_t)(((b * Wd + (Wd - 1)) * Nd + i)) * (Nd * Ed);
  for (int idx = tid; idx < Nd * Ed; idx += 256) ef_sh[idx] = efrow[idx];
  const float* adjrow = adj + (b * Nd + i) * Nd;
  if (tid < Nd) adj_sh[tid] = adjrow[tid];
  if (tid < Hd) hcur[tid] = h0[row * Hd + tid];
  __syncthreads();

  // ---- wsum: p[e] = sum_j adj*edge[e], p[5] = sum_j adj (order as before)
  float p[6] = {0.f, 0.f, 0.f, 0.f, 0.f, 0.f};
  if (tid < Nd) {
    float a = adj_sh[tid];
    p[5] = a;
    #pragma unroll
    for (int k = 0; k < Ed; ++k) p[k] = a * ef_sh[tid * Ed + k];
  }
  #pragma unroll
  for (int k = 0; k < 6; ++k) {
    float v = p[k];
    for (int off = 32; off > 0; off >>= 1) v += __shfl_down(v, off);
    p[k] = v;
  }
  if ((tid & 63) == 0) {
    #pragma unroll
    for (int k = 0; k < 6; ++k) red[tid >> 6][k] = p[k];
  }
  __syncthreads();
  if (tid < 6)
    w6[tid] = red[0][tid] + red[1][tid] + red[2][tid] + red[3][tid];
  __syncthreads();

  // ---- 2 GCN rounds (wave 0; coalesced transposed-weight reads)
  const int u = tid & 63;
  #pragma unroll
  for (int round = 0; round < 2; ++round) {
    float hnew = 0.f;
    if (tid < 64) {
      const float* gwT = gcnWT + round * 4096;   // [k][u]
      const float* ewT = epWT  + round * 320;    // [e][u]
      float acc = gcn_b[round * Hd + u] + w6[5] * ep_b[round * Hd + u];
      #pragma unroll
      for (int e = 0; e < Ed; ++e) acc += w6[e] * ewT[e * 64 + u];
      #pragma unroll 8
      for (int k = 0; k < Hd; ++k) acc += hcur[k] * gwT[k * 64 + u];

      float mu = acc;
      #pragma unroll
      for (int off = 1; off < 64; off <<= 1) mu += __shfl_xor(mu, off);
      mu *= (1.f / 64.f);
      float d = acc - mu;
      float var = d * d;
      #pragma unroll
      for (int off = 1; off < 64; off <<= 1) var += __shfl_xor(var, off);
      var *= (1.f / 64.f);
      float v = d * rsqrtf(var + LNEPS) * ln_g[round * Hd + u] + ln_b[round * Hd + u];
      hnew = fmaxf(v, 0.f);
    }
    __syncthreads();               // all reads of hcur done
    if (tid < 64) hcur[tid] = hnew;
    __syncthreads();
  }

  // ---- u/v precompute (threads 0..127; coalesced transposed W1 reads)
  if (tid < 64) {
    float acc = b1[tid];
    #pragma unroll 8
    for (int k = 0; k < Hd; ++k) acc += hcur[k] * W1aT[k * 64 + tid];
    uu[row * Hd + tid] = acc;
  } else if (tid < 128) {
    const int n = tid - 64;
    float acc = 0.f;
    #pragma unroll 8
    for (int k = 0; k < Hd; ++k) acc += hcur[k] * W1bT[k * 64 + n];
    vt[n * NSEQ + row] = acc;
  }
}

// --------------------------------------------------------------------------
// Edge MLP: thread per edge. z1[64] lives in VGPRs; W1c/W2/W3/b2 have
// wave-uniform indices -> scalar-pipe loads, fmac v,s,v at VALU issue peak.
// (R9 version.)
__global__ __launch_bounds__(256) void k_mlp(
    const float* __restrict__ ef,
    const float* __restrict__ u, const float* __restrict__ vt,
    const float* __restrict__ W1,
    const float* __restrict__ W2, const float* __restrict__ b2,
    const float* __restrict__ W3, const float* __restrict__ b3,
    float* __restrict__ out)
{
  const int idx = blockIdx.x * 256 + threadIdx.x;   // < 320000
  const int b   = idx / (Nd * Nd);
  const int rem = idx - b * Nd * Nd;
  const int i   = rem / Nd;
  const int jj  = rem - i * Nd;

  const float* e = ef + (((b * Wd + (Wd - 1)) * Nd + i) * Nd + jj) * Ed;
  float e5[Ed];
  #pragma unroll
  for (int q = 0; q < Ed; ++q) e5[q] = e[q];

  const float* ur = u + (b * Nd + i) * Hd;
  const int vcol = b * Nd + jj;

  float z1[64];
  #pragma unroll
  for (int k = 0; k < 64; ++k) {
    float acc = ur[k] + vt[k * NSEQ + vcol];
    const float* w1c = W1 + k * 133 + 128;      // uniform -> scalar loads
    #pragma unroll
    for (int q = 0; q < Ed; ++q) acc += e5[q] * w1c[q];
    z1[k] = fmaxf(acc, 0.f);
  }

  float logit = b3[0];
  #pragma unroll 4
  for (int o = 0; o < 32; ++o) {
    float a0 = b2[o], a1 = 0.f, a2 = 0.f, a3 = 0.f;
    const float* w2 = W2 + o * 64;              // uniform -> scalar loads
    #pragma unroll
    for (int k = 0; k < 64; k += 4) {
      a0 += w2[k]     * z1[k];
      a1 += w2[k + 1] * z1[k + 1];
      a2 += w2[k + 2] * z1[k + 2];
      a3 += w2[k + 3] * z1[k + 3];
    }
    float z2 = fmaxf((a0 + a1) + (a2 + a3), 0.f);
    logit += W3[o] * z2;
  }
  out[idx] = 1.f / (1.f + __expf(-logit));
}

// --------------------------------------------------------------------------
extern "C" void kernel_launch(void* const* d_in, const int* in_sizes, int n_in,
                              void* d_out, int out_size, void* d_ws, size_t ws_size,
                              hipStream_t stream) {
  (void)in_sizes; (void)n_in; (void)out_size; (void)ws_size;
  const float* nf   = (const float*)d_in[0];
  const float* ef   = (const float*)d_in[1];
  const float* adj  = (const float*)d_in[2];
  const float* Wih0 = (const float*)d_in[3];
  const float* Whh0 = (const float*)d_in[4];
  const float* bih0 = (const float*)d_in[5];
  const float* bhh0 = (const float*)d_in[6];
  const float* Wih1 = (const float*)d_in[7];
  const float* Whh1 = (const float*)d_in[8];
  const float* bih1 = (const float*)d_in[9];
  const float* bhh1 = (const float*)d_in[10];
  const float* gcnW = (const float*)d_in[11];
  const float* gcnB = (const float*)d_in[12];
  const float* epW  = (const float*)d_in[13];
  const float* epB  = (const float*)d_in[14];
  const float* lnG  = (const float*)d_in[15];
  const float* lnB  = (const float*)d_in[16];
  const float* W1   = (const float*)d_in[17];
  const float* b1   = (const float*)d_in[18];
  const float* W2   = (const float*)d_in[19];
  const float* b2   = (const float*)d_in[20];
  const float* W3   = (const float*)d_in[21];
  const float* b3   = (const float*)d_in[22];
  float* out = (float*)d_out;

  // Workspace layout (floats).
  float* ws   = (float*)d_ws;
  float* h0   = ws;                        // 102,400
  float* uu   = h0   + 102400;             // 102,400
  float* vt   = uu   + 102400;             // 102,400
  float* gWT  = vt   + 102400;             // 8,192
  float* eWT  = gWT  + 8192;               // 640
  float* W1aT = eWT  + 640;                // 4,096
  float* W1bT = W1aT + 4096;               // 4,096

  k_prep      <<<67,        256, 0, stream>>>(gcnW, epW, W1, gWT, eWT, W1aT, W1bT);
  k_lstm_fused<<<NSEQ/SEQPB,512, 0, stream>>>(nf, Wih0, Whh0, bih0, bhh0,
                                              Wih1, Whh1, bih1, bhh1, h0);
  k_node      <<<1600,      256, 0, stream>>>(ef, adj, h0, gWT, gcnB, eWT, epB,
                                              lnG, lnB, W1aT, W1bT, b1, uu, vt);
  k_mlp       <<<1250,      256, 0, stream>>>(ef, uu, vt, W1, W2, b2, W3, b3, out);
}

// Round 5
// 390.646 us; speedup vs baseline: 1.9932x; 1.9932x over previous
//
#include <hip/hip_runtime.h>
#include <math.h>

// ---------------------------------------------------------------------------
// TemporalGCN: 2-layer LSTM (per-node sequences) -> 2 GCN rounds -> edge MLP.
//
// R13: R12 post-mortem: 473MB FETCH / 347MB WRITE = scratch thrash caused by
// declaring FIVE float4[16] weight arrays (320 floats) whose live ranges the
// allocator must union across divergent role branches. Invariant from R9
// (proven: 128 wfloats -> VGPR 116 + AGPR overflow, zero mem spill):
// <=128 weight floats per thread, in arrays SHARED by all roles.
// New structure: 384 threads = 3 roles x 2 waves, every role r=2 rows/thread
// via one shared wA[16]/wB[16] pair:
//   role 0 (tid<128):    L0 gates rows (jsub, jsub+128)   -- reads h0_sh
//   role 1 (128..255):   xproj rows -> x1_sh[t&1]          -- reads h0_sh
//   role 2 (256..383):   L1 gates rows, seed x1_sh[(t-1)&1]-- reads h1_sh
// DS/phase: 768 b128 (vs R9 1536) ~ 7.7K cyc -> predicted ~55us.
// Updates: tid<256 L0 (verbatim R9 (w,u)->{w,w+4}); tid>=256 L1 (4 states,
// static unroll). 14 phases, 2 barriers each (hazards as R12, re-verified).
//
// Bit-exactness: per-output accumulation chains verbatim (a1 takes x-dot
// first, quarter-split q-loop, (a0+a1)+(a2+a3), +bias1 before seeding,
// c = fv*c + iv*gv) -> absmax 0.0 preserved.
// ---------------------------------------------------------------------------

#define Hd   64
#define Ed   5
#define Fd   6
#define Bd   8
#define Wd   12
#define Nd   200
#define NSEQ (Bd*Nd)        // 1600 sequences (b,n)
#define NG   (4*Hd)         // 256 gate rows
#define SEQPB 8             // sequences per fused-LSTM block (200 % 8 == 0)
#define LNEPS 1e-5f

__device__ __forceinline__ float sigm(float x) { return 1.0f / (1.0f + __expf(-x)); }
__device__ __forceinline__ float tanh_fast(float x) {
  float ax = fabsf(x);
  float t  = __expf(-2.0f * ax);
  float r  = (1.0f - t) / (1.0f + t);
  return copysignf(r, x);
}

// --------------------------------------------------------------------------
// Prep: gcnWT[round][k][u]; epWT[round][e][u]; W1aT[k][n]=W1[n][k];
// W1bT[k][n]=W1[n][64+k]. Sizes: 8192 + 640 + 4096 + 4096 = 17024 elements.
__global__ __launch_bounds__(256) void k_prep(
    const float* __restrict__ gcn_W, const float* __restrict__ ep_W,
    const float* __restrict__ W1,
    float* __restrict__ gcnWT, float* __restrict__ epWT,
    float* __restrict__ W1aT, float* __restrict__ W1bT)
{
  int idx = blockIdx.x * 256 + threadIdx.x;
  if (idx < 8192) {                        // gcnWT[r][k][u] = gcn_W[r][u][k]
    int round = idx >> 12, rem = idx & 4095;
    int k = rem >> 6, u = rem & 63;
    gcnWT[idx] = gcn_W[round * 4096 + u * 64 + k];
  } else if (idx < 8832) {                 // epWT[r][e][u] = ep_W[r][u][e]
    int r0 = idx - 8192;
    int round = r0 / 320, rem = r0 % 320;
    int e = rem >> 6, u = rem & 63;
    epWT[r0] = ep_W[round * 320 + u * Ed + e];
  } else if (idx < 12928) {                // W1aT[k][n] = W1[n][k]
    int r0 = idx - 8832;
    int k = r0 >> 6, n = r0 & 63;
    W1aT[r0] = W1[n * 133 + k];
  } else if (idx < 17024) {                // W1bT[k][n] = W1[n][64+k]
    int r0 = idx - 12928;
    int k = r0 >> 6, n = r0 & 63;
    W1bT[r0] = W1[n * 133 + 64 + k];
  }
}

// --------------------------------------------------------------------------
// Fused 2-layer LSTM. 200 blocks x 384 threads (6 waves), 8 seqs/block.
// Phase t in [0,13]:
//   role 0: L0 gates step t (t<12)           rows jsub, jsub+128
//   role 1: xproj xv(t-1) (1<=t<=12)         rows jsub, jsub+128
//   role 2: L1 gates step t-2 (t>=2)         rows jsub, jsub+128
// barrier; L0 update (tid<256), L1 update (tid>=256, 4 states); barrier.
__global__ __launch_bounds__(384, 1) void k_lstm_fused(
    const float* __restrict__ nf,                       // (B,W,N,F)
    const float* __restrict__ Wih0, const float* __restrict__ Whh0,
    const float* __restrict__ bih0, const float* __restrict__ bhh0,
    const float* __restrict__ Wih1, const float* __restrict__ Whh1,
    const float* __restrict__ bih1, const float* __restrict__ bhh1,
    float* __restrict__ hout)                           // (NSEQ, H)
{
  __shared__ float x_sh[SEQPB][Wd * Fd];   // 576
  __shared__ float h0_sh[SEQPB][Hd];       // 512
  __shared__ float h1_sh[SEQPB][Hd];       // 512
  __shared__ float g0_sh[SEQPB][NG];       // 2048 (post-activation gates L0)
  __shared__ float g1_sh[SEQPB][NG];       // 2048 (post-activation gates L1)
  __shared__ float x1_sh[2][SEQPB][NG];    // 4096 (xv = Wih1.h0 + bias1)

  const int tid  = threadIdx.x;
  const int seq0 = blockIdx.x * SEQPB;
  const int b    = seq0 / Nd;              // uniform (200 % 8 == 0)
  const int n0   = seq0 % Nd;

  for (int idx = tid; idx < SEQPB * Wd * Fd; idx += 384) {
    int s = idx / (Wd * Fd), r = idx - s * (Wd * Fd);
    int t = r / Fd, f = r - t * Fd;
    x_sh[s][r] = nf[((b * Wd + t) * Nd + (n0 + s)) * Fd + f];
  }
  for (int idx = tid; idx < SEQPB * Hd; idx += 384) {
    ((float*)h0_sh)[idx] = 0.f;
    ((float*)h1_sh)[idx] = 0.f;
  }

  const int role = tid >> 7;               // 0: L0, 1: xproj, 2: L1
  const int jsub = tid & 127;              // row-lo; row-hi = jsub+128
  const int u    = tid & 63;
  const int w    = (tid >> 6) & 3;         // L0 update ownership (tid<256)
  const int w2   = (tid >> 6) & 1;         // L1 update ownership (tid>=256)
  // Activation selectors (wave-uniform): rows jsub -> gates 0/1 (sigm);
  // rows jsub+128 -> gates 2/3 (tanh for 2, sigm for 3).
  const int jtA = jsub >> 6;               // 0 or 1
  const int jtB = 2 + (jsub >> 6);         // 2 or 3

  // ---- SHARED per-role weight registers: max 128 wfloats + 12 + 2 ----
  float4 wA[16], wB[16];
  float  wxA[Fd], wxB[Fd];
  float  biasA = 0.f, biasB = 0.f;
  if (role == 0) {
    const float4* ra = (const float4*)(Whh0 + jsub * Hd);
    const float4* rb = (const float4*)(Whh0 + (jsub + 128) * Hd);
    #pragma unroll
    for (int q = 0; q < 16; ++q) { wA[q] = ra[q]; wB[q] = rb[q]; }
    #pragma unroll
    for (int f = 0; f < Fd; ++f) {
      wxA[f] = Wih0[jsub * Fd + f];
      wxB[f] = Wih0[(jsub + 128) * Fd + f];
    }
    biasA = bih0[jsub] + bhh0[jsub];
    biasB = bih0[jsub + 128] + bhh0[jsub + 128];
  } else if (role == 1) {
    const float4* ra = (const float4*)(Wih1 + jsub * Hd);
    const float4* rb = (const float4*)(Wih1 + (jsub + 128) * Hd);
    #pragma unroll
    for (int q = 0; q < 16; ++q) { wA[q] = ra[q]; wB[q] = rb[q]; }
    biasA = bih1[jsub] + bhh1[jsub];
    biasB = bih1[jsub + 128] + bhh1[jsub + 128];
  } else {
    const float4* ra = (const float4*)(Whh1 + jsub * Hd);
    const float4* rb = (const float4*)(Whh1 + (jsub + 128) * Hd);
    #pragma unroll
    for (int q = 0; q < 16; ++q) { wA[q] = ra[q]; wB[q] = rb[q]; }
  }

  // Update-ownership state (loop-carried registers).
  float cA = 0.f, cB = 0.f, hA = 0.f, hB = 0.f;        // tid<256: L0
  float cs[4] = {0.f, 0.f, 0.f, 0.f};                  // tid>=256: L1
  float hs[4] = {0.f, 0.f, 0.f, 0.f};
  __syncthreads();

  for (int t = 0; t <= Wd + 1; ++t) {
    // ================= gate section ======================================
    if (role == 0) {
      if (t < Wd) {                        // L0 gates step t, rows jsub/jsub+128
        #pragma unroll 2
        for (int s = 0; s < SEQPB; ++s) {
          const float* xp = &x_sh[s][t * Fd];
          float a0 = biasA, a1 = 0.f, a2 = 0.f, a3 = 0.f;
          float e0 = biasB, e1 = 0.f, e2 = 0.f, e3 = 0.f;
          #pragma unroll
          for (int f = 0; f < Fd; ++f) a1 += xp[f] * wxA[f];
          #pragma unroll
          for (int f = 0; f < Fd; ++f) e1 += xp[f] * wxB[f];
          const float4* h4 = (const float4*)h0_sh[s];
          #pragma unroll
          for (int q = 0; q < 16; ++q) {
            float4 hv = h4[q];
            float dA = hv.x * wA[q].x + hv.y * wA[q].y + hv.z * wA[q].z + hv.w * wA[q].w;
            float dB = hv.x * wB[q].x + hv.y * wB[q].y + hv.z * wB[q].z + hv.w * wB[q].w;
            if ((q & 3) == 0) { a0 += dA; e0 += dB; }
            else if ((q & 3) == 1) { a1 += dA; e1 += dB; }
            else if ((q & 3) == 2) { a2 += dA; e2 += dB; }
            else { a3 += dA; e3 += dB; }
          }
          float accA = (a0 + a1) + (a2 + a3);
          float accB = (e0 + e1) + (e2 + e3);
          g0_sh[s][jsub]       = (jtA == 2) ? tanh_fast(accA) : sigm(accA);
          g0_sh[s][jsub + 128] = (jtB == 2) ? tanh_fast(accB) : sigm(accB);
        }
      }
    } else if (role == 1) {
      if (t >= 1 && t <= Wd) {             // xv(t-1): one h0 b128, two rows
        #pragma unroll 2
        for (int s = 0; s < SEQPB; ++s) {
          const float4* h4 = (const float4*)h0_sh[s];
          float xa = 0.f, xb = 0.f;
          #pragma unroll
          for (int q = 0; q < 16; ++q) {
            float4 hv = h4[q];
            xa = fmaf(hv.x, wA[q].x, xa);
            xa = fmaf(hv.y, wA[q].y, xa);
            xa = fmaf(hv.z, wA[q].z, xa);
            xa = fmaf(hv.w, wA[q].w, xa);
            xb = fmaf(hv.x, wB[q].x, xb);
            xb = fmaf(hv.y, wB[q].y, xb);
            xb = fmaf(hv.z, wB[q].z, xb);
            xb = fmaf(hv.w, wB[q].w, xb);
          }
          x1_sh[t & 1][s][jsub]       = xa + biasA;
          x1_sh[t & 1][s][jsub + 128] = xb + biasB;
        }
      }
    } else {
      if (t >= 2) {                        // L1 gates step t-2, rows jsub/+128
        #pragma unroll 2
        for (int s = 0; s < SEQPB; ++s) {
          const float* xv = x1_sh[(t - 1) & 1][s];   // xv(t-2), written t-1
          float a0 = xv[jsub],       a1 = 0.f, a2 = 0.f, a3 = 0.f;
          float e0 = xv[jsub + 128], e1 = 0.f, e2 = 0.f, e3 = 0.f;
          const float4* h4 = (const float4*)h1_sh[s];
          #pragma unroll
          for (int q = 0; q < 16; ++q) {
            float4 hv = h4[q];
            float dA = hv.x * wA[q].x + hv.y * wA[q].y + hv.z * wA[q].z + hv.w * wA[q].w;
            float dB = hv.x * wB[q].x + hv.y * wB[q].y + hv.z * wB[q].z + hv.w * wB[q].w;
            if ((q & 3) == 0) { a0 += dA; e0 += dB; }
            else if ((q & 3) == 1) { a1 += dA; e1 += dB; }
            else if ((q & 3) == 2) { a2 += dA; e2 += dB; }
            else { a3 += dA; e3 += dB; }
          }
          float accA = (a0 + a1) + (a2 + a3);
          float accB = (e0 + e1) + (e2 + e3);
          g1_sh[s][jsub]       = (jtA == 2) ? tanh_fast(accA) : sigm(accA);
          g1_sh[s][jsub + 128] = (jtB == 2) ? tanh_fast(accB) : sigm(accB);
        }
      }
    }
    __syncthreads();                       // gates/xv ready; h reads done

    // ================= update section ====================================
    if (tid < 256) {
      if (t < Wd) {                        // L0 update step t (verbatim R9)
        const float* gb = g0_sh[w];
        float iv = gb[u], fv = gb[64 + u], gv = gb[128 + u], ov = gb[192 + u];
        cA = fv * cA + iv * gv;
        hA = ov * tanh_fast(cA);
        h0_sh[w][u] = hA;
        const float* gb2 = g0_sh[w + 4];
        float iv2 = gb2[u], fv2 = gb2[64 + u], gv2 = gb2[128 + u], ov2 = gb2[192 + u];
        cB = fv2 * cB + iv2 * gv2;
        hB = ov2 * tanh_fast(cB);
        h0_sh[w + 4][u] = hB;
      }
    } else {
      if (t >= 2) {                        // L1 update step t-2 (4 states)
        #pragma unroll
        for (int q2 = 0; q2 < 4; ++q2) {
          const int s = w2 + 2 * q2;
          const float* gb = g1_sh[s];
          float iv = gb[u], fv = gb[64 + u], gv = gb[128 + u], ov = gb[192 + u];
          cs[q2] = fv * cs[q2] + iv * gv;
          hs[q2] = ov * tanh_fast(cs[q2]);
          h1_sh[s][u] = hs[q2];
        }
      }
    }
    __syncthreads();                       // h writes visible to next phase
  }

  // Final h1(11) -> hout from L1 update owners (tid>=256). Coalesced.
  if (tid >= 256) {
    #pragma unroll
    for (int q2 = 0; q2 < 4; ++q2)
      hout[(seq0 + w2 + 2 * q2) * Hd + u] = hs[q2];
  }
}

// --------------------------------------------------------------------------
// Fused per-row node pipeline: wsum -> GCN r0 -> GCN r1 -> u/v precompute.
// One block per row (b,i); 256 threads. adj/ef rows staged into LDS with
// COALESCED loads; all weight reads coalesced via the k_prep transposes.
__global__ __launch_bounds__(256) void k_node(
    const float* __restrict__ ef,    const float* __restrict__ adj,
    const float* __restrict__ h0,
    const float* __restrict__ gcnWT, const float* __restrict__ gcn_b,
    const float* __restrict__ epWT,  const float* __restrict__ ep_b,
    const float* __restrict__ ln_g,  const float* __restrict__ ln_b,
    const float* __restrict__ W1aT,  const float* __restrict__ W1bT,
    const float* __restrict__ b1,
    float* __restrict__ uu, float* __restrict__ vt)
{
  __shared__ float ef_sh[Nd * Ed];   // 1000: edge_last row (coalesced stage)
  __shared__ float adj_sh[Nd];       // 200
  __shared__ float red[4][6];
  __shared__ float w6[6];
  __shared__ float hcur[Hd];

  const int row = blockIdx.x;      // b*200+i
  const int b = row / Nd, i = row % Nd;
  const int tid = threadIdx.x;

  const float* efrow = ef + (size_t)(((b * Wd + (Wd - 1)) * Nd + i)) * (Nd * Ed);
  for (int idx = tid; idx < Nd * Ed; idx += 256) ef_sh[idx] = efrow[idx];
  const float* adjrow = adj + (b * Nd + i) * Nd;
  if (tid < Nd) adj_sh[tid] = adjrow[tid];
  if (tid < Hd) hcur[tid] = h0[row * Hd + tid];
  __syncthreads();

  // ---- wsum: p[e] = sum_j adj*edge[e], p[5] = sum_j adj (order as before)
  float p[6] = {0.f, 0.f, 0.f, 0.f, 0.f, 0.f};
  if (tid < Nd) {
    float a = adj_sh[tid];
    p[5] = a;
    #pragma unroll
    for (int k = 0; k < Ed; ++k) p[k] = a * ef_sh[tid * Ed + k];
  }
  #pragma unroll
  for (int k = 0; k < 6; ++k) {
    float v = p[k];
    for (int off = 32; off > 0; off >>= 1) v += __shfl_down(v, off);
    p[k] = v;
  }
  if ((tid & 63) == 0) {
    #pragma unroll
    for (int k = 0; k < 6; ++k) red[tid >> 6][k] = p[k];
  }
  __syncthreads();
  if (tid < 6)
    w6[tid] = red[0][tid] + red[1][tid] + red[2][tid] + red[3][tid];
  __syncthreads();

  // ---- 2 GCN rounds (wave 0; coalesced transposed-weight reads)
  const int u = tid & 63;
  #pragma unroll
  for (int round = 0; round < 2; ++round) {
    float hnew = 0.f;
    if (tid < 64) {
      const float* gwT = gcnWT + round * 4096;   // [k][u]
      const float* ewT = epWT  + round * 320;    // [e][u]
      float acc = gcn_b[round * Hd + u] + w6[5] * ep_b[round * Hd + u];
      #pragma unroll
      for (int e = 0; e < Ed; ++e) acc += w6[e] * ewT[e * 64 + u];
      #pragma unroll 8
      for (int k = 0; k < Hd; ++k) acc += hcur[k] * gwT[k * 64 + u];

      float mu = acc;
      #pragma unroll
      for (int off = 1; off < 64; off <<= 1) mu += __shfl_xor(mu, off);
      mu *= (1.f / 64.f);
      float d = acc - mu;
      float var = d * d;
      #pragma unroll
      for (int off = 1; off < 64; off <<= 1) var += __shfl_xor(var, off);
      var *= (1.f / 64.f);
      float v = d * rsqrtf(var + LNEPS) * ln_g[round * Hd + u] + ln_b[round * Hd + u];
      hnew = fmaxf(v, 0.f);
    }
    __syncthreads();               // all reads of hcur done
    if (tid < 64) hcur[tid] = hnew;
    __syncthreads();
  }

  // ---- u/v precompute (threads 0..127; coalesced transposed W1 reads)
  if (tid < 64) {
    float acc = b1[tid];
    #pragma unroll 8
    for (int k = 0; k < Hd; ++k) acc += hcur[k] * W1aT[k * 64 + tid];
    uu[row * Hd + tid] = acc;
  } else if (tid < 128) {
    const int n = tid - 64;
    float acc = 0.f;
    #pragma unroll 8
    for (int k = 0; k < Hd; ++k) acc += hcur[k] * W1bT[k * 64 + n];
    vt[n * NSEQ + row] = acc;
  }
}

// --------------------------------------------------------------------------
// Edge MLP: thread per edge. z1[64] lives in VGPRs; W1c/W2/W3/b2 have
// wave-uniform indices -> scalar-pipe loads, fmac v,s,v at VALU issue peak.
__global__ __launch_bounds__(256) void k_mlp(
    const float* __restrict__ ef,
    const float* __restrict__ u, const float* __restrict__ vt,
    const float* __restrict__ W1,
    const float* __restrict__ W2, const float* __restrict__ b2,
    const float* __restrict__ W3, const float* __restrict__ b3,
    float* __restrict__ out)
{
  const int idx = blockIdx.x * 256 + threadIdx.x;   // < 320000
  const int b   = idx / (Nd * Nd);
  const int rem = idx - b * Nd * Nd;
  const int i   = rem / Nd;
  const int jj  = rem - i * Nd;

  const float* e = ef + (((b * Wd + (Wd - 1)) * Nd + i) * Nd + jj) * Ed;
  float e5[Ed];
  #pragma unroll
  for (int q = 0; q < Ed; ++q) e5[q] = e[q];

  const float* ur = u + (b * Nd + i) * Hd;
  const int vcol = b * Nd + jj;

  float z1[64];
  #pragma unroll
  for (int k = 0; k < 64; ++k) {
    float acc = ur[k] + vt[k * NSEQ + vcol];
    const float* w1c = W1 + k * 133 + 128;      // uniform -> scalar loads
    #pragma unroll
    for (int q = 0; q < Ed; ++q) acc += e5[q] * w1c[q];
    z1[k] = fmaxf(acc, 0.f);
  }

  float logit = b3[0];
  #pragma unroll 4
  for (int o = 0; o < 32; ++o) {
    float a0 = b2[o], a1 = 0.f, a2 = 0.f, a3 = 0.f;
    const float* w2 = W2 + o * 64;              // uniform -> scalar loads
    #pragma unroll
    for (int k = 0; k < 64; k += 4) {
      a0 += w2[k]     * z1[k];
      a1 += w2[k + 1] * z1[k + 1];
      a2 += w2[k + 2] * z1[k + 2];
      a3 += w2[k + 3] * z1[k + 3];
    }
    float z2 = fmaxf((a0 + a1) + (a2 + a3), 0.f);
    logit += W3[o] * z2;
  }
  out[idx] = 1.f / (1.f + __expf(-logit));
}

// --------------------------------------------------------------------------
extern "C" void kernel_launch(void* const* d_in, const int* in_sizes, int n_in,
                              void* d_out, int out_size, void* d_ws, size_t ws_size,
                              hipStream_t stream) {
  (void)in_sizes; (void)n_in; (void)out_size; (void)ws_size;
  const float* nf   = (const float*)d_in[0];
  const float* ef   = (const float*)d_in[1];
  const float* adj  = (const float*)d_in[2];
  const float* Wih0 = (const float*)d_in[3];
  const float* Whh0 = (const float*)d_in[4];
  const float* bih0 = (const float*)d_in[5];
  const float* bhh0 = (const float*)d_in[6];
  const float* Wih1 = (const float*)d_in[7];
  const float* Whh1 = (const float*)d_in[8];
  const float* bih1 = (const float*)d_in[9];
  const float* bhh1 = (const float*)d_in[10];
  const float* gcnW = (const float*)d_in[11];
  const float* gcnB = (const float*)d_in[12];
  const float* epW  = (const float*)d_in[13];
  const float* epB  = (const float*)d_in[14];
  const float* lnG  = (const float*)d_in[15];
  const float* lnB  = (const float*)d_in[16];
  const float* W1   = (const float*)d_in[17];
  const float* b1   = (const float*)d_in[18];
  const float* W2   = (const float*)d_in[19];
  const float* b2   = (const float*)d_in[20];
  const float* W3   = (const float*)d_in[21];
  const float* b3   = (const float*)d_in[22];
  float* out = (float*)d_out;

  // Workspace layout (floats).
  float* ws   = (float*)d_ws;
  float* h0   = ws;                        // 102,400
  float* uu   = h0   + 102400;             // 102,400
  float* vt   = uu   + 102400;             // 102,400
  float* gWT  = vt   + 102400;             // 8,192
  float* eWT  = gWT  + 8192;               // 640
  float* W1aT = eWT  + 640;                // 4,096
  float* W1bT = W1aT + 4096;               // 4,096

  k_prep      <<<67,        256, 0, stream>>>(gcnW, epW, W1, gWT, eWT, W1aT, W1bT);
  k_lstm_fused<<<NSEQ/SEQPB,384, 0, stream>>>(nf, Wih0, Whh0, bih0, bhh0,
                                              Wih1, Whh1, bih1, bhh1, h0);
  k_node      <<<1600,      256, 0, stream>>>(ef, adj, h0, gWT, gcnB, eWT, epB,
                                              lnG, lnB, W1aT, W1bT, b1, uu, vt);
  k_mlp       <<<1250,      256, 0, stream>>>(ef, uu, vt, W1, W2, b2, W3, b3, out);
}

// Round 6
// 349.131 us; speedup vs baseline: 2.2302x; 1.1189x over previous
//
#include <hip/hip_runtime.h>
#include <math.h>

// ---------------------------------------------------------------------------
// TemporalGCN: 2-layer LSTM (per-node sequences) -> 2 GCN rounds -> edge MLP.
//
// R14: conservative single-delta from the proven R9 kernel (84.5us, VGPR 116,
// no spill). Register-safety envelope established by R9-R13:
//   SAFE:  128 weight floats/thread + ~15 working values (R9 B-threads)
//   SPILL: >=134 weight floats or 128 + dual-row accumulator sets (R11/R13)
// Change: move the xproj from B to A, evicting A's wx[6] to LDS, so A becomes
// a mirror of R9's proven B-thread: Whh0 row j + Wih1 row j = exactly 128 wf.
// A's single h0 ds_read_b128 stream feeds BOTH the L0 gate dot and the xproj
// fmaf chain; xv flows through parity-double-buffered x1_sh (R11's validated
// 14-phase schedule). B holds only Whh1 row j (64 wf) and seeds a0 from x1_sh.
// DS/phase: 1536 b128 (R9: B re-read h0 AND h1) -> 1024 b128 = the structural
// floor for 8 waves x 8 seqs with <=128 wf/thread. Predicted ~70us.
// The Wih0 x-dot reads wx_sh[j*6+f] from LDS: 2-way bank conflict == free.
//
// Spill tripwire for the post-mortem: FETCH ~1.2MB / WRITE ~0.4MB expected;
// multi-MB values mean scratch thrash -> revert to R9 verbatim.
//
// Bit-exactness: all accumulation chains verbatim (a1 ascending-f x-dot,
// quarter-split a0..a3 float4 dot, xacc fmaf chain + single bias1 add,
// c = fv*c + iv*gv) -> absmax 0.0 preserved.
// ---------------------------------------------------------------------------

#define Hd   64
#define Ed   5
#define Fd   6
#define Bd   8
#define Wd   12
#define Nd   200
#define NSEQ (Bd*Nd)        // 1600 sequences (b,n)
#define NG   (4*Hd)         // 256 gate rows
#define SEQPB 8             // sequences per fused-LSTM block (200 % 8 == 0)
#define LNEPS 1e-5f

__device__ __forceinline__ float sigm(float x) { return 1.0f / (1.0f + __expf(-x)); }
__device__ __forceinline__ float tanh_fast(float x) {
  float ax = fabsf(x);
  float t  = __expf(-2.0f * ax);
  float r  = (1.0f - t) / (1.0f + t);
  return copysignf(r, x);
}

// --------------------------------------------------------------------------
// Prep: gcnWT[round][k][u]; epWT[round][e][u]; W1aT[k][n]=W1[n][k];
// W1bT[k][n]=W1[n][64+k]. Sizes: 8192 + 640 + 4096 + 4096 = 17024 elements.
__global__ __launch_bounds__(256) void k_prep(
    const float* __restrict__ gcn_W, const float* __restrict__ ep_W,
    const float* __restrict__ W1,
    float* __restrict__ gcnWT, float* __restrict__ epWT,
    float* __restrict__ W1aT, float* __restrict__ W1bT)
{
  int idx = blockIdx.x * 256 + threadIdx.x;
  if (idx < 8192) {                        // gcnWT[r][k][u] = gcn_W[r][u][k]
    int round = idx >> 12, rem = idx & 4095;
    int k = rem >> 6, u = rem & 63;
    gcnWT[idx] = gcn_W[round * 4096 + u * 64 + k];
  } else if (idx < 8832) {                 // epWT[r][e][u] = ep_W[r][u][e]
    int r0 = idx - 8192;
    int round = r0 / 320, rem = r0 % 320;
    int e = rem >> 6, u = rem & 63;
    epWT[r0] = ep_W[round * 320 + u * Ed + e];
  } else if (idx < 12928) {                // W1aT[k][n] = W1[n][k]
    int r0 = idx - 8832;
    int k = r0 >> 6, n = r0 & 63;
    W1aT[r0] = W1[n * 133 + k];
  } else if (idx < 17024) {                // W1bT[k][n] = W1[n][64+k]
    int r0 = idx - 12928;
    int k = r0 >> 6, n = r0 & 63;
    W1bT[r0] = W1[n * 133 + 64 + k];
  }
}

// --------------------------------------------------------------------------
// Fused 2-layer LSTM. 200 blocks x 512 threads, 8 seqs/block.
// Phase t in [0,13]:
//   A waves (tid<256): L0 gates step t (t<12) + xproj xv(t-1) (1<=t<=12),
//     both off the SAME h0_sh b128 stream. A = Whh0[j] + Wih1[j] = 128 wf.
//   B waves: L1 gates step t-2 (t>=2), a0 seeded from x1_sh[(t-1)&1].
// barrier; L0 update (tid<256), L1 update (tid>=256) -- verbatim R9; barrier.
__global__ __launch_bounds__(512, 2) void k_lstm_fused(
    const float* __restrict__ nf,                       // (B,W,N,F)
    const float* __restrict__ Wih0, const float* __restrict__ Whh0,
    const float* __restrict__ bih0, const float* __restrict__ bhh0,
    const float* __restrict__ Wih1, const float* __restrict__ Whh1,
    const float* __restrict__ bih1, const float* __restrict__ bhh1,
    float* __restrict__ hout)                           // (NSEQ, H)
{
  __shared__ float x_sh[SEQPB][Wd * Fd];   // 576
  __shared__ float wx_sh[NG * Fd];         // 1536: Wih0 rows (same layout)
  __shared__ float h0_sh[SEQPB][Hd];       // 512
  __shared__ float h1_sh[SEQPB][Hd];       // 512
  __shared__ float g0_sh[SEQPB][NG];       // 2048 (post-activation gates L0)
  __shared__ float g1_sh[SEQPB][NG];       // 2048 (post-activation gates L1)
  __shared__ float x1_sh[2][SEQPB][NG];    // 4096 (xv = Wih1.h0 + bias1)

  const int tid  = threadIdx.x;
  const int seq0 = blockIdx.x * SEQPB;
  const int b    = seq0 / Nd;              // uniform (200 % 8 == 0)
  const int n0   = seq0 % Nd;

  for (int idx = tid; idx < SEQPB * Wd * Fd; idx += 512) {
    int s = idx / (Wd * Fd), r = idx - s * (Wd * Fd);
    int t = r / Fd, f = r - t * Fd;
    x_sh[s][r] = nf[((b * Wd + t) * Nd + (n0 + s)) * Fd + f];
  }
  for (int idx = tid; idx < NG * Fd; idx += 512)
    wx_sh[idx] = Wih0[idx];                // linear copy (row-major match)
  ((float*)h0_sh)[tid] = 0.f;              // 512 floats, one per thread
  ((float*)h1_sh)[tid] = 0.f;

  const bool isA = (tid < 256);
  const int j  = tid & 255;                // gate row within this layer
  const int jt = j >> 6;                   // 0=i,1=f,2=g,3=o (wave-uniform)
  const int u  = tid & 63;
  const int w  = (tid >> 6) & 3;           // update ownership: seqs {w, w+4}

  // Per-thread weights (registers): A = Whh0[j] + Wih1[j] (128 wf, the
  // R9-proven budget); B = Whh1[j] (64 wf).
  float4 wh[16];                           // Whh0 row j (A) / Whh1 row j (B)
  float4 wi1[16];                          // Wih1 row j (A only)
  float  bias0 = 0.f, bias1 = 0.f;
  if (isA) {
    const float4* wr = (const float4*)(Whh0 + j * Hd);
    #pragma unroll
    for (int q = 0; q < 16; ++q) wh[q] = wr[q];
    const float4* xr = (const float4*)(Wih1 + j * Hd);
    #pragma unroll
    for (int q = 0; q < 16; ++q) wi1[q] = xr[q];
    bias0 = bih0[j] + bhh0[j];
    bias1 = bih1[j] + bhh1[j];
  } else {
    const float4* wr = (const float4*)(Whh1 + j * Hd);
    #pragma unroll
    for (int q = 0; q < 16; ++q) wh[q] = wr[q];
  }

  float cA = 0.f, cB = 0.f;                // cell states for seqs w, w+4
  float hA = 0.f, hB = 0.f;                // B threads: final h1 for w, w+4
  const float* wxp = wx_sh + j * Fd;       // A's Wih0 row (LDS, 2-way = free)
  __syncthreads();

  for (int t = 0; t <= Wd + 1; ++t) {
    // ================= gate section ======================================
    if (isA) {
      if (t < Wd) {                        // L0 gates step t + xproj xv(t-1)
        #pragma unroll 2
        for (int s = 0; s < SEQPB; ++s) {
          const float* xp = &x_sh[s][t * Fd];
          float a0 = bias0, a1 = 0.f, a2 = 0.f, a3 = 0.f;
          #pragma unroll
          for (int f = 0; f < Fd; ++f) a1 += xp[f] * wxp[f];
          float xacc = 0.f;
          const float4* h4 = (const float4*)h0_sh[s];
          #pragma unroll
          for (int q = 0; q < 16; ++q) {
            float4 hv = h4[q];                      // ONE b128, two dots
            float d = hv.x * wh[q].x + hv.y * wh[q].y + hv.z * wh[q].z + hv.w * wh[q].w;
            if ((q & 3) == 0) a0 += d; else if ((q & 3) == 1) a1 += d;
            else if ((q & 3) == 2) a2 += d; else a3 += d;
            xacc = fmaf(hv.x, wi1[q].x, xacc);      // xproj for L1 step t-1
            xacc = fmaf(hv.y, wi1[q].y, xacc);
            xacc = fmaf(hv.z, wi1[q].z, xacc);
            xacc = fmaf(hv.w, wi1[q].w, xacc);
          }
          float acc = (a0 + a1) + (a2 + a3);
          g0_sh[s][j] = (jt == 2) ? tanh_fast(acc) : sigm(acc);
          if (t >= 1) x1_sh[t & 1][s][j] = xacc + bias1;
        }
      } else if (t == Wd) {                // t==12: xv(11) only
        #pragma unroll 2
        for (int s = 0; s < SEQPB; ++s) {
          float xacc = 0.f;
          const float4* h4 = (const float4*)h0_sh[s];
          #pragma unroll
          for (int q = 0; q < 16; ++q) {
            float4 hv = h4[q];
            xacc = fmaf(hv.x, wi1[q].x, xacc);
            xacc = fmaf(hv.y, wi1[q].y, xacc);
            xacc = fmaf(hv.z, wi1[q].z, xacc);
            xacc = fmaf(hv.w, wi1[q].w, xacc);
          }
          x1_sh[t & 1][s][j] = xacc + bias1;
        }
      }
    } else {
      if (t >= 2) {                        // L1 gates step t-2
        #pragma unroll 2
        for (int s = 0; s < SEQPB; ++s) {
          float a0 = x1_sh[(t - 1) & 1][s][j];   // xv(t-2), written phase t-1
          float a1 = 0.f, a2 = 0.f, a3 = 0.f;
          const float4* h4 = (const float4*)h1_sh[s];
          #pragma unroll
          for (int q = 0; q < 16; ++q) {
            float4 hv = h4[q];
            float d = hv.x * wh[q].x + hv.y * wh[q].y + hv.z * wh[q].z + hv.w * wh[q].w;
            if ((q & 3) == 0) a0 += d; else if ((q & 3) == 1) a1 += d;
            else if ((q & 3) == 2) a2 += d; else a3 += d;
          }
          float acc = (a0 + a1) + (a2 + a3);
          g1_sh[s][j] = (jt == 2) ? tanh_fast(acc) : sigm(acc);
        }
      }
    }
    __syncthreads();                       // gates/xv ready; all h reads done

    // ================= update section (verbatim R9 ownership) ============
    if (isA) {
      if (t < Wd) {                        // L0 update step t
        const float* gb = g0_sh[w];
        float iv = gb[u], fv = gb[64 + u], gv = gb[128 + u], ov = gb[192 + u];
        cA = fv * cA + iv * gv;
        hA = ov * tanh_fast(cA);
        h0_sh[w][u] = hA;
        const float* gb2 = g0_sh[w + 4];
        float iv2 = gb2[u], fv2 = gb2[64 + u], gv2 = gb2[128 + u], ov2 = gb2[192 + u];
        cB = fv2 * cB + iv2 * gv2;
        hB = ov2 * tanh_fast(cB);
        h0_sh[w + 4][u] = hB;
      }
    } else {
      if (t >= 2) {                        // L1 update step t-2
        const float* gb = g1_sh[w];
        float iv = gb[u], fv = gb[64 + u], gv = gb[128 + u], ov = gb[192 + u];
        cA = fv * cA + iv * gv;
        hA = ov * tanh_fast(cA);
        h1_sh[w][u] = hA;
        const float* gb2 = g1_sh[w + 4];
        float iv2 = gb2[u], fv2 = gb2[64 + u], gv2 = gb2[128 + u], ov2 = gb2[192 + u];
        cB = fv2 * cB + iv2 * gv2;
        hB = ov2 * tanh_fast(cB);
        h1_sh[w + 4][u] = hB;
      }
    }
    __syncthreads();                       // h writes visible to next phase
  }

  // Final h1(11) -> hout from B threads' partitioned state. Coalesced.
  if (!isA) {
    hout[(seq0 + w) * Hd + u]     = hA;
    hout[(seq0 + w + 4) * Hd + u] = hB;
  }
}

// --------------------------------------------------------------------------
// Fused per-row node pipeline: wsum -> GCN r0 -> GCN r1 -> u/v precompute.
// One block per row (b,i); 256 threads. adj/ef rows staged into LDS with
// COALESCED loads; all weight reads coalesced via the k_prep transposes.
__global__ __launch_bounds__(256) void k_node(
    const float* __restrict__ ef,    const float* __restrict__ adj,
    const float* __restrict__ h0,
    const float* __restrict__ gcnWT, const float* __restrict__ gcn_b,
    const float* __restrict__ epWT,  const float* __restrict__ ep_b,
    const float* __restrict__ ln_g,  const float* __restrict__ ln_b,
    const float* __restrict__ W1aT,  const float* __restrict__ W1bT,
    const float* __restrict__ b1,
    float* __restrict__ uu, float* __restrict__ vt)
{
  __shared__ float ef_sh[Nd * Ed];   // 1000: edge_last row (coalesced stage)
  __shared__ float adj_sh[Nd];       // 200
  __shared__ float red[4][6];
  __shared__ float w6[6];
  __shared__ float hcur[Hd];

  const int row = blockIdx.x;      // b*200+i
  const int b = row / Nd, i = row % Nd;
  const int tid = threadIdx.x;

  const float* efrow = ef + (size_t)(((b * Wd + (Wd - 1)) * Nd + i)) * (Nd * Ed);
  for (int idx = tid; idx < Nd * Ed; idx += 256) ef_sh[idx] = efrow[idx];
  const float* adjrow = adj + (b * Nd + i) * Nd;
  if (tid < Nd) adj_sh[tid] = adjrow[tid];
  if (tid < Hd) hcur[tid] = h0[row * Hd + tid];
  __syncthreads();

  // ---- wsum: p[e] = sum_j adj*edge[e], p[5] = sum_j adj (order as before)
  float p[6] = {0.f, 0.f, 0.f, 0.f, 0.f, 0.f};
  if (tid < Nd) {
    float a = adj_sh[tid];
    p[5] = a;
    #pragma unroll
    for (int k = 0; k < Ed; ++k) p[k] = a * ef_sh[tid * Ed + k];
  }
  #pragma unroll
  for (int k = 0; k < 6; ++k) {
    float v = p[k];
    for (int off = 32; off > 0; off >>= 1) v += __shfl_down(v, off);
    p[k] = v;
  }
  if ((tid & 63) == 0) {
    #pragma unroll
    for (int k = 0; k < 6; ++k) red[tid >> 6][k] = p[k];
  }
  __syncthreads();
  if (tid < 6)
    w6[tid] = red[0][tid] + red[1][tid] + red[2][tid] + red[3][tid];
  __syncthreads();

  // ---- 2 GCN rounds (wave 0; coalesced transposed-weight reads)
  const int u = tid & 63;
  #pragma unroll
  for (int round = 0; round < 2; ++round) {
    float hnew = 0.f;
    if (tid < 64) {
      const float* gwT = gcnWT + round * 4096;   // [k][u]
      const float* ewT = epWT  + round * 320;    // [e][u]
      float acc = gcn_b[round * Hd + u] + w6[5] * ep_b[round * Hd + u];
      #pragma unroll
      for (int e = 0; e < Ed; ++e) acc += w6[e] * ewT[e * 64 + u];
      #pragma unroll 8
      for (int k = 0; k < Hd; ++k) acc += hcur[k] * gwT[k * 64 + u];

      float mu = acc;
      #pragma unroll
      for (int off = 1; off < 64; off <<= 1) mu += __shfl_xor(mu, off);
      mu *= (1.f / 64.f);
      float d = acc - mu;
      float var = d * d;
      #pragma unroll
      for (int off = 1; off < 64; off <<= 1) var += __shfl_xor(var, off);
      var *= (1.f / 64.f);
      float v = d * rsqrtf(var + LNEPS) * ln_g[round * Hd + u] + ln_b[round * Hd + u];
      hnew = fmaxf(v, 0.f);
    }
    __syncthreads();               // all reads of hcur done
    if (tid < 64) hcur[tid] = hnew;
    __syncthreads();
  }

  // ---- u/v precompute (threads 0..127; coalesced transposed W1 reads)
  if (tid < 64) {
    float acc = b1[tid];
    #pragma unroll 8
    for (int k = 0; k < Hd; ++k) acc += hcur[k] * W1aT[k * 64 + tid];
    uu[row * Hd + tid] = acc;
  } else if (tid < 128) {
    const int n = tid - 64;
    float acc = 0.f;
    #pragma unroll 8
    for (int k = 0; k < Hd; ++k) acc += hcur[k] * W1bT[k * 64 + n];
    vt[n * NSEQ + row] = acc;
  }
}

// --------------------------------------------------------------------------
// Edge MLP: thread per edge. z1[64] lives in VGPRs; W1c/W2/W3/b2 have
// wave-uniform indices -> scalar-pipe loads, fmac v,s,v at VALU issue peak.
__global__ __launch_bounds__(256) void k_mlp(
    const float* __restrict__ ef,
    const float* __restrict__ u, const float* __restrict__ vt,
    const float* __restrict__ W1,
    const float* __restrict__ W2, const float* __restrict__ b2,
    const float* __restrict__ W3, const float* __restrict__ b3,
    float* __restrict__ out)
{
  const int idx = blockIdx.x * 256 + threadIdx.x;   // < 320000
  const int b   = idx / (Nd * Nd);
  const int rem = idx - b * Nd * Nd;
  const int i   = rem / Nd;
  const int jj  = rem - i * Nd;

  const float* e = ef + (((b * Wd + (Wd - 1)) * Nd + i) * Nd + jj) * Ed;
  float e5[Ed];
  #pragma unroll
  for (int q = 0; q < Ed; ++q) e5[q] = e[q];

  const float* ur = u + (b * Nd + i) * Hd;
  const int vcol = b * Nd + jj;

  float z1[64];
  #pragma unroll
  for (int k = 0; k < 64; ++k) {
    float acc = ur[k] + vt[k * NSEQ + vcol];
    const float* w1c = W1 + k * 133 + 128;      // uniform -> scalar loads
    #pragma unroll
    for (int q = 0; q < Ed; ++q) acc += e5[q] * w1c[q];
    z1[k] = fmaxf(acc, 0.f);
  }

  float logit = b3[0];
  #pragma unroll 4
  for (int o = 0; o < 32; ++o) {
    float a0 = b2[o], a1 = 0.f, a2 = 0.f, a3 = 0.f;
    const float* w2 = W2 + o * 64;              // uniform -> scalar loads
    #pragma unroll
    for (int k = 0; k < 64; k += 4) {
      a0 += w2[k]     * z1[k];
      a1 += w2[k + 1] * z1[k + 1];
      a2 += w2[k + 2] * z1[k + 2];
      a3 += w2[k + 3] * z1[k + 3];
    }
    float z2 = fmaxf((a0 + a1) + (a2 + a3), 0.f);
    logit += W3[o] * z2;
  }
  out[idx] = 1.f / (1.f + __expf(-logit));
}

// --------------------------------------------------------------------------
extern "C" void kernel_launch(void* const* d_in, const int* in_sizes, int n_in,
                              void* d_out, int out_size, void* d_ws, size_t ws_size,
                              hipStream_t stream) {
  (void)in_sizes; (void)n_in; (void)out_size; (void)ws_size;
  const float* nf   = (const float*)d_in[0];
  const float* ef   = (const float*)d_in[1];
  const float* adj  = (const float*)d_in[2];
  const float* Wih0 = (const float*)d_in[3];
  const float* Whh0 = (const float*)d_in[4];
  const float* bih0 = (const float*)d_in[5];
  const float* bhh0 = (const float*)d_in[6];
  const float* Wih1 = (const float*)d_in[7];
  const float* Whh1 = (const float*)d_in[8];
  const float* bih1 = (const float*)d_in[9];
  const float* bhh1 = (const float*)d_in[10];
  const float* gcnW = (const float*)d_in[11];
  const float* gcnB = (const float*)d_in[12];
  const float* epW  = (const float*)d_in[13];
  const float* epB  = (const float*)d_in[14];
  const float* lnG  = (const float*)d_in[15];
  const float* lnB  = (const float*)d_in[16];
  const float* W1   = (const float*)d_in[17];
  const float* b1   = (const float*)d_in[18];
  const float* W2   = (const float*)d_in[19];
  const float* b2   = (const float*)d_in[20];
  const float* W3   = (const float*)d_in[21];
  const float* b3   = (const float*)d_in[22];
  float* out = (float*)d_out;

  // Workspace layout (floats).
  float* ws   = (float*)d_ws;
  float* h0   = ws;                        // 102,400
  float* uu   = h0   + 102400;             // 102,400
  float* vt   = uu   + 102400;             // 102,400
  float* gWT  = vt   + 102400;             // 8,192
  float* eWT  = gWT  + 8192;               // 640
  float* W1aT = eWT  + 640;                // 4,096
  float* W1bT = W1aT + 4096;               // 4,096

  k_prep      <<<67,        256, 0, stream>>>(gcnW, epW, W1, gWT, eWT, W1aT, W1bT);
  k_lstm_fused<<<NSEQ/SEQPB,512, 0, stream>>>(nf, Wih0, Whh0, bih0, bhh0,
                                              Wih1, Whh1, bih1, bhh1, h0);
  k_node      <<<1600,      256, 0, stream>>>(ef, adj, h0, gWT, gcnB, eWT, epB,
                                              lnG, lnB, W1aT, W1bT, b1, uu, vt);
  k_mlp       <<<1250,      256, 0, stream>>>(ef, uu, vt, W1, W2, b2, W3, b3, out);
}

// Round 7
// 273.206 us; speedup vs baseline: 2.8499x; 1.2779x over previous
//
#include <hip/hip_runtime.h>
#include <math.h>

// ---------------------------------------------------------------------------
// TemporalGCN: 2-layer LSTM (per-node sequences) -> 2 GCN rounds -> edge MLP.
//
// R15: consolidation + one parameter. R10-R14 post-mortems established that
// every DS-reduction restructure needs >=128 weight floats/thread somewhere,
// and that configuration is allocator-fragile (4/5 attempts spilled to
// scratch; only R9's exact B-thread shape compiled clean at VGPR 116).
// So: R9's kernel VERBATIM (measured 84.5us, FETCH 1.16MB, no spill), with
// SEQPB 8 -> 4 (grid 200 -> 400). All inner code identical; per-thread
// state strictly smaller (1 owned seq, not 2). Rationale: R9 ran 1 block/CU
// (200 blocks < 256 CUs, 56 CUs idle); its 15.6K cyc/phase = 12.3K DS +
// 3.3K barrier/VALU overhead a single block can't hide. At SEQPB=4,
// launch_bounds(512,2) fits TWO blocks/CU (4 waves/SIMD x 116 regs = 464
// <= 512; LDS ~12KB x2) -> one block's barrier drain overlaps the other's
// DS issue -> CU approaches the pure-DS floor. Total DS unchanged
// (redundancy = waves/block = 8), so this targets ONLY the 21% overhead.
// Verification signals: OccupancyPercent ~2x (17 -> ~34); FETCH/WRITE must
// stay ~1.3MB/0.4MB (spill tripwire); lstm ~68-72us predicted.
//
// Bit-exactness: identical accumulation expressions per (seq,unit); only
// the thread->sequence ownership map changes -> absmax 0.0 preserved.
// ---------------------------------------------------------------------------

#define Hd   64
#define Ed   5
#define Fd   6
#define Bd   8
#define Wd   12
#define Nd   200
#define NSEQ (Bd*Nd)        // 1600 sequences (b,n)
#define NG   (4*Hd)         // 256 gate rows
#define SEQPB 4             // sequences per fused-LSTM block (200 % 4 == 0)
#define LNEPS 1e-5f

__device__ __forceinline__ float sigm(float x) { return 1.0f / (1.0f + __expf(-x)); }
__device__ __forceinline__ float tanh_fast(float x) {
  float ax = fabsf(x);
  float t  = __expf(-2.0f * ax);
  float r  = (1.0f - t) / (1.0f + t);
  return copysignf(r, x);
}

// --------------------------------------------------------------------------
// Prep: gcnWT[round][k][u]; epWT[round][e][u]; W1aT[k][n]=W1[n][k];
// W1bT[k][n]=W1[n][64+k]. Sizes: 8192 + 640 + 4096 + 4096 = 17024 elements.
__global__ __launch_bounds__(256) void k_prep(
    const float* __restrict__ gcn_W, const float* __restrict__ ep_W,
    const float* __restrict__ W1,
    float* __restrict__ gcnWT, float* __restrict__ epWT,
    float* __restrict__ W1aT, float* __restrict__ W1bT)
{
  int idx = blockIdx.x * 256 + threadIdx.x;
  if (idx < 8192) {                        // gcnWT[r][k][u] = gcn_W[r][u][k]
    int round = idx >> 12, rem = idx & 4095;
    int k = rem >> 6, u = rem & 63;
    gcnWT[idx] = gcn_W[round * 4096 + u * 64 + k];
  } else if (idx < 8832) {                 // epWT[r][e][u] = ep_W[r][u][e]
    int r0 = idx - 8192;
    int round = r0 / 320, rem = r0 % 320;
    int e = rem >> 6, u = rem & 63;
    epWT[r0] = ep_W[round * 320 + u * Ed + e];
  } else if (idx < 12928) {                // W1aT[k][n] = W1[n][k]
    int r0 = idx - 8832;
    int k = r0 >> 6, n = r0 & 63;
    W1aT[r0] = W1[n * 133 + k];
  } else if (idx < 17024) {                // W1bT[k][n] = W1[n][64+k]
    int r0 = idx - 12928;
    int k = r0 >> 6, n = r0 & 63;
    W1bT[r0] = W1[n * 133 + 64 + k];
  }
}

// --------------------------------------------------------------------------
// Fused 2-layer LSTM (R9 structure, SEQPB=4). 400 blocks x 512 threads.
// Waves 0-3 (A): thread j = layer-0 gate j for all 4 seqs.
// Waves 4-7 (B): thread j = layer-1 gate j, one step behind (xproj fused:
//   B reads h0_sh for the Wih1 dot, h1_sh for the Whh1 dot).
// Phase t in [0,12]: A computes L0 step t (t<12), B computes L1 step t-1.
// Each phase: gates -> barrier -> c/h update (thread (w,u) owns seq w) ->
// barrier. No global stores until the end (hout only).
__global__ __launch_bounds__(512, 2) void k_lstm_fused(
    const float* __restrict__ nf,                       // (B,W,N,F)
    const float* __restrict__ Wih0, const float* __restrict__ Whh0,
    const float* __restrict__ bih0, const float* __restrict__ bhh0,
    const float* __restrict__ Wih1, const float* __restrict__ Whh1,
    const float* __restrict__ bih1, const float* __restrict__ bhh1,
    float* __restrict__ hout)                           // (NSEQ, H)
{
  __shared__ float x_sh[SEQPB][Wd * Fd];   // 288
  __shared__ float h0_sh[SEQPB][Hd];       // 256
  __shared__ float h1_sh[SEQPB][Hd];       // 256
  __shared__ float g0_sh[SEQPB][NG];       // 1024 (post-activation gates L0)
  __shared__ float g1_sh[SEQPB][NG];       // 1024 (post-activation gates L1)

  const int tid  = threadIdx.x;
  const int seq0 = blockIdx.x * SEQPB;
  const int b    = seq0 / Nd;              // uniform across block (200%4==0)
  const int n0   = seq0 % Nd;

  // Stage x for all 4 sequences (288 floats), zero h states.
  for (int idx = tid; idx < SEQPB * Wd * Fd; idx += 512) {
    int s = idx / (Wd * Fd), r = idx - s * (Wd * Fd);
    int t = r / Fd, f = r - t * Fd;
    x_sh[s][r] = nf[((b * Wd + t) * Nd + (n0 + s)) * Fd + f];
  }
  if (tid < SEQPB * Hd) {                  // 256 floats each
    ((float*)h0_sh)[tid] = 0.f;
    ((float*)h1_sh)[tid] = 0.f;
  }

  const bool isA = (tid < 256);
  const int j  = tid & 255;                // gate row within this layer
  const int jt = j >> 6;                   // 0=i,1=f,2=g,3=o (wave-uniform)
  const int u  = tid & 63;
  const int w  = (tid >> 6) & 3;           // owns seq w in the update

  // Per-thread weights (registers) -- identical shapes to R9 (VGPR 116).
  float4 wh[16];                           // Whh0 row j (A) / Whh1 row j (B)
  float4 wi1[16];                          // Wih1 row j (B only)
  float  wx[Fd];                           // Wih0 row j (A only)
  float  bias;
  if (isA) {
    const float4* wr = (const float4*)(Whh0 + j * Hd);
    #pragma unroll
    for (int q = 0; q < 16; ++q) wh[q] = wr[q];
    #pragma unroll
    for (int f = 0; f < Fd; ++f) wx[f] = Wih0[j * Fd + f];
    bias = bih0[j] + bhh0[j];
  } else {
    const float4* wr = (const float4*)(Whh1 + j * Hd);
    #pragma unroll
    for (int q = 0; q < 16; ++q) wh[q] = wr[q];
    const float4* xr = (const float4*)(Wih1 + j * Hd);
    #pragma unroll
    for (int q = 0; q < 16; ++q) wi1[q] = xr[q];
    bias = bih1[j] + bhh1[j];
  }

  float cA = 0.f;                          // cell state for owned seq w
  float hA = 0.f;                          // last h (B threads: final output)
  __syncthreads();

  for (int t = 0; t <= Wd; ++t) {
    // ---- gate computation (reads h0_sh/h1_sh state from previous phase)
    if (isA) {
      if (t < Wd) {
        #pragma unroll 2
        for (int s = 0; s < SEQPB; ++s) {
          const float* xp = &x_sh[s][t * Fd];
          float a0 = bias, a1 = 0.f, a2 = 0.f, a3 = 0.f;
          #pragma unroll
          for (int f = 0; f < Fd; ++f) a1 += xp[f] * wx[f];
          const float4* h4 = (const float4*)h0_sh[s];
          #pragma unroll
          for (int q = 0; q < 16; ++q) {
            float4 hv = h4[q];
            float d = hv.x * wh[q].x + hv.y * wh[q].y + hv.z * wh[q].z + hv.w * wh[q].w;
            if ((q & 3) == 0) a0 += d; else if ((q & 3) == 1) a1 += d;
            else if ((q & 3) == 2) a2 += d; else a3 += d;
          }
          float acc = (a0 + a1) + (a2 + a3);
          g0_sh[s][j] = (jt == 2) ? tanh_fast(acc) : sigm(acc);
        }
      }
    } else {
      if (t >= 1) {
        #pragma unroll 2
        for (int s = 0; s < SEQPB; ++s) {
          // x-projection: y0[t-1] == current h0_sh[s]; ascending-k fmaf chain
          // then one add of (bih1+bhh1) -- identical order to R9.
          const float4* y4 = (const float4*)h0_sh[s];
          float xacc = 0.f;
          #pragma unroll
          for (int q = 0; q < 16; ++q) {
            float4 yv = y4[q];
            xacc = fmaf(yv.x, wi1[q].x, xacc);
            xacc = fmaf(yv.y, wi1[q].y, xacc);
            xacc = fmaf(yv.z, wi1[q].z, xacc);
            xacc = fmaf(yv.w, wi1[q].w, xacc);
          }
          xacc += bias;
          // recurrent projection: identical structure to R9.
          float a0 = xacc, a1 = 0.f, a2 = 0.f, a3 = 0.f;
          const float4* h4 = (const float4*)h1_sh[s];
          #pragma unroll
          for (int q = 0; q < 16; ++q) {
            float4 hv = h4[q];
            float d = hv.x * wh[q].x + hv.y * wh[q].y + hv.z * wh[q].z + hv.w * wh[q].w;
            if ((q & 3) == 0) a0 += d; else if ((q & 3) == 1) a1 += d;
            else if ((q & 3) == 2) a2 += d; else a3 += d;
          }
          float acc = (a0 + a1) + (a2 + a3);
          g1_sh[s][j] = (jt == 2) ? tanh_fast(acc) : sigm(acc);
        }
      }
    }
    __syncthreads();                       // gates ready; all h reads done

    // ---- c/h update: thread (wave w, lane u) owns (seq w, unit u)
    if (isA) {
      if (t < Wd) {
        const float* gb = g0_sh[w];
        float iv = gb[u], fv = gb[64 + u], gv = gb[128 + u], ov = gb[192 + u];
        cA = fv * cA + iv * gv;
        hA = ov * tanh_fast(cA);
        h0_sh[w][u] = hA;
      }
    } else {
      if (t >= 1) {
        const float* gb = g1_sh[w];
        float iv = gb[u], fv = gb[64 + u], gv = gb[128 + u], ov = gb[192 + u];
        cA = fv * cA + iv * gv;
        hA = ov * tanh_fast(cA);
        h1_sh[w][u] = hA;
      }
    }
    __syncthreads();                       // h writes visible to next phase
  }

  // Final h of layer 1 (= y1[:, -1]) -> hout. Coalesced (u consecutive).
  if (!isA) {
    hout[(seq0 + w) * Hd + u] = hA;
  }
}

// --------------------------------------------------------------------------
// Fused per-row node pipeline: wsum -> GCN r0 -> GCN r1 -> u/v precompute.
// One block per row (b,i); 256 threads. adj/ef rows staged into LDS with
// COALESCED loads; all weight reads coalesced via the k_prep transposes.
__global__ __launch_bounds__(256) void k_node(
    const float* __restrict__ ef,    const float* __restrict__ adj,
    const float* __restrict__ h0,
    const float* __restrict__ gcnWT, const float* __restrict__ gcn_b,
    const float* __restrict__ epWT,  const float* __restrict__ ep_b,
    const float* __restrict__ ln_g,  const float* __restrict__ ln_b,
    const float* __restrict__ W1aT,  const float* __restrict__ W1bT,
    const float* __restrict__ b1,
    float* __restrict__ uu, float* __restrict__ vt)
{
  __shared__ float ef_sh[Nd * Ed];   // 1000: edge_last row (coalesced stage)
  __shared__ float adj_sh[Nd];       // 200
  __shared__ float red[4][6];
  __shared__ float w6[6];
  __shared__ float hcur[Hd];

  const int row = blockIdx.x;      // b*200+i
  const int b = row / Nd, i = row % Nd;
  const int tid = threadIdx.x;

  const float* efrow = ef + (size_t)(((b * Wd + (Wd - 1)) * Nd + i)) * (Nd * Ed);
  for (int idx = tid; idx < Nd * Ed; idx += 256) ef_sh[idx] = efrow[idx];
  const float* adjrow = adj + (b * Nd + i) * Nd;
  if (tid < Nd) adj_sh[tid] = adjrow[tid];
  if (tid < Hd) hcur[tid] = h0[row * Hd + tid];
  __syncthreads();

  // ---- wsum: p[e] = sum_j adj*edge[e], p[5] = sum_j adj (order as before)
  float p[6] = {0.f, 0.f, 0.f, 0.f, 0.f, 0.f};
  if (tid < Nd) {
    float a = adj_sh[tid];
    p[5] = a;
    #pragma unroll
    for (int k = 0; k < Ed; ++k) p[k] = a * ef_sh[tid * Ed + k];
  }
  #pragma unroll
  for (int k = 0; k < 6; ++k) {
    float v = p[k];
    for (int off = 32; off > 0; off >>= 1) v += __shfl_down(v, off);
    p[k] = v;
  }
  if ((tid & 63) == 0) {
    #pragma unroll
    for (int k = 0; k < 6; ++k) red[tid >> 6][k] = p[k];
  }
  __syncthreads();
  if (tid < 6)
    w6[tid] = red[0][tid] + red[1][tid] + red[2][tid] + red[3][tid];
  __syncthreads();

  // ---- 2 GCN rounds (wave 0; coalesced transposed-weight reads)
  const int u = tid & 63;
  #pragma unroll
  for (int round = 0; round < 2; ++round) {
    float hnew = 0.f;
    if (tid < 64) {
      const float* gwT = gcnWT + round * 4096;   // [k][u]
      const float* ewT = epWT  + round * 320;    // [e][u]
      float acc = gcn_b[round * Hd + u] + w6[5] * ep_b[round * Hd + u];
      #pragma unroll
      for (int e = 0; e < Ed; ++e) acc += w6[e] * ewT[e * 64 + u];
      #pragma unroll 8
      for (int k = 0; k < Hd; ++k) acc += hcur[k] * gwT[k * 64 + u];

      float mu = acc;
      #pragma unroll
      for (int off = 1; off < 64; off <<= 1) mu += __shfl_xor(mu, off);
      mu *= (1.f / 64.f);
      float d = acc - mu;
      float var = d * d;
      #pragma unroll
      for (int off = 1; off < 64; off <<= 1) var += __shfl_xor(var, off);
      var *= (1.f / 64.f);
      float v = d * rsqrtf(var + LNEPS) * ln_g[round * Hd + u] + ln_b[round * Hd + u];
      hnew = fmaxf(v, 0.f);
    }
    __syncthreads();               // all reads of hcur done
    if (tid < 64) hcur[tid] = hnew;
    __syncthreads();
  }

  // ---- u/v precompute (threads 0..127; coalesced transposed W1 reads)
  if (tid < 64) {
    float acc = b1[tid];
    #pragma unroll 8
    for (int k = 0; k < Hd; ++k) acc += hcur[k] * W1aT[k * 64 + tid];
    uu[row * Hd + tid] = acc;
  } else if (tid < 128) {
    const int n = tid - 64;
    float acc = 0.f;
    #pragma unroll 8
    for (int k = 0; k < Hd; ++k) acc += hcur[k] * W1bT[k * 64 + n];
    vt[n * NSEQ + row] = acc;
  }
}

// --------------------------------------------------------------------------
// Edge MLP: thread per edge. z1[64] lives in VGPRs; W1c/W2/W3/b2 have
// wave-uniform indices -> scalar-pipe loads, fmac v,s,v at VALU issue peak.
__global__ __launch_bounds__(256) void k_mlp(
    const float* __restrict__ ef,
    const float* __restrict__ u, const float* __restrict__ vt,
    const float* __restrict__ W1,
    const float* __restrict__ W2, const float* __restrict__ b2,
    const float* __restrict__ W3, const float* __restrict__ b3,
    float* __restrict__ out)
{
  const int idx = blockIdx.x * 256 + threadIdx.x;   // < 320000
  const int b   = idx / (Nd * Nd);
  const int rem = idx - b * Nd * Nd;
  const int i   = rem / Nd;
  const int jj  = rem - i * Nd;

  const float* e = ef + (((b * Wd + (Wd - 1)) * Nd + i) * Nd + jj) * Ed;
  float e5[Ed];
  #pragma unroll
  for (int q = 0; q < Ed; ++q) e5[q] = e[q];

  const float* ur = u + (b * Nd + i) * Hd;
  const int vcol = b * Nd + jj;

  float z1[64];
  #pragma unroll
  for (int k = 0; k < 64; ++k) {
    float acc = ur[k] + vt[k * NSEQ + vcol];
    const float* w1c = W1 + k * 133 + 128;      // uniform -> scalar loads
    #pragma unroll
    for (int q = 0; q < Ed; ++q) acc += e5[q] * w1c[q];
    z1[k] = fmaxf(acc, 0.f);
  }

  float logit = b3[0];
  #pragma unroll 4
  for (int o = 0; o < 32; ++o) {
    float a0 = b2[o], a1 = 0.f, a2 = 0.f, a3 = 0.f;
    const float* w2 = W2 + o * 64;              // uniform -> scalar loads
    #pragma unroll
    for (int k = 0; k < 64; k += 4) {
      a0 += w2[k]     * z1[k];
      a1 += w2[k + 1] * z1[k + 1];
      a2 += w2[k + 2] * z1[k + 2];
      a3 += w2[k + 3] * z1[k + 3];
    }
    float z2 = fmaxf((a0 + a1) + (a2 + a3), 0.f);
    logit += W3[o] * z2;
  }
  out[idx] = 1.f / (1.f + __expf(-logit));
}

// --------------------------------------------------------------------------
extern "C" void kernel_launch(void* const* d_in, const int* in_sizes, int n_in,
                              void* d_out, int out_size, void* d_ws, size_t ws_size,
                              hipStream_t stream) {
  (void)in_sizes; (void)n_in; (void)out_size; (void)ws_size;
  const float* nf   = (const float*)d_in[0];
  const float* ef   = (const float*)d_in[1];
  const float* adj  = (const float*)d_in[2];
  const float* Wih0 = (const float*)d_in[3];
  const float* Whh0 = (const float*)d_in[4];
  const float* bih0 = (const float*)d_in[5];
  const float* bhh0 = (const float*)d_in[6];
  const float* Wih1 = (const float*)d_in[7];
  const float* Whh1 = (const float*)d_in[8];
  const float* bih1 = (const float*)d_in[9];
  const float* bhh1 = (const float*)d_in[10];
  const float* gcnW = (const float*)d_in[11];
  const float* gcnB = (const float*)d_in[12];
  const float* epW  = (const float*)d_in[13];
  const float* epB  = (const float*)d_in[14];
  const float* lnG  = (const float*)d_in[15];
  const float* lnB  = (const float*)d_in[16];
  const float* W1   = (const float*)d_in[17];
  const float* b1   = (const float*)d_in[18];
  const float* W2   = (const float*)d_in[19];
  const float* b2   = (const float*)d_in[20];
  const float* W3   = (const float*)d_in[21];
  const float* b3   = (const float*)d_in[22];
  float* out = (float*)d_out;

  // Workspace layout (floats).
  float* ws   = (float*)d_ws;
  float* h0   = ws;                        // 102,400
  float* uu   = h0   + 102400;             // 102,400
  float* vt   = uu   + 102400;             // 102,400
  float* gWT  = vt   + 102400;             // 8,192
  float* eWT  = gWT  + 8192;               // 640
  float* W1aT = eWT  + 640;                // 4,096
  float* W1bT = W1aT + 4096;               // 4,096

  k_prep      <<<67,        256, 0, stream>>>(gcnW, epW, W1, gWT, eWT, W1aT, W1bT);
  k_lstm_fused<<<NSEQ/SEQPB,512, 0, stream>>>(nf, Wih0, Whh0, bih0, bhh0,
                                              Wih1, Whh1, bih1, bhh1, h0);
  k_node      <<<1600,      256, 0, stream>>>(ef, adj, h0, gWT, gcnB, eWT, epB,
                                              lnG, lnB, W1aT, W1bT, b1, uu, vt);
  k_mlp       <<<1250,      256, 0, stream>>>(ef, uu, vt, W1, W2, b2, W3, b3, out);
}

// Round 8
// 259.491 us; speedup vs baseline: 3.0006x; 1.0529x over previous
//
#include <hip/hip_runtime.h>
#include <math.h>

// ---------------------------------------------------------------------------
// TemporalGCN: 2-layer LSTM (per-node sequences) -> 2 GCN rounds -> edge MLP.
//
// R16: R15 disproved the co-residency theory (DS return path is per-CU:
// two co-resident blocks contend; 94.5us > R9's 84.5). Back to SEQPB=8.
// Remaining lever: DS volume. R14's structure (A owns BOTH Whh0[j] and
// Wih1[j]; one h0 b128 stream feeds gate dot + xproj; B owns Whh1[j] only,
// seeded from parity-buffered x1_sh) cut DS/phase 1536 -> 1024 b128 but
// spilled. Spill dataset across R9-R15 says the 128-wf config compiles
// clean ONLY with plain __launch_bounds__(512) (R10: 134 wf -> VGPR 92,
// AGPR-backed, FETCH 1.35MB) and a single un-duplicated loop body.
// R16 = R14 structure + those two fixes:
//   - __launch_bounds__(512) (no min-waves hint -> allocator may use AGPRs)
//   - x_sh padded to 13 t-columns (zeros) so t==12 runs the same fused
//     body (gate result simply not stored) -- no duplicated xproj tail.
// Phase t in [0,13]: A: L0 gate t (t<12) + xv(t-1) (1<=t<=12); B: L1 step
// t-2 (t>=2). DS/phase: A 512 b128 (h0) + B 512 b128 (h1). ~73us predicted.
// Spill tripwire: FETCH <=1.5MB / WRITE <=0.5MB; multi-MB -> revert to R9.
//
// Bit-exactness: all accumulation chains verbatim (a1 ascending-f x-dot,
// quarter-split a0..a3 float4 dot, xacc ascending-q fmaf chain + single
// bias1 add, c = fv*c + iv*gv) -> absmax 0.0 preserved.
// ---------------------------------------------------------------------------

#define Hd   64
#define Ed   5
#define Fd   6
#define Bd   8
#define Wd   12
#define Nd   200
#define NSEQ (Bd*Nd)        // 1600 sequences (b,n)
#define NG   (4*Hd)         // 256 gate rows
#define SEQPB 8             // sequences per fused-LSTM block (200 % 8 == 0)
#define WP   (Wd + 1)       // padded t-columns in x_sh (col 12 = zeros)
#define LNEPS 1e-5f

__device__ __forceinline__ float sigm(float x) { return 1.0f / (1.0f + __expf(-x)); }
__device__ __forceinline__ float tanh_fast(float x) {
  float ax = fabsf(x);
  float t  = __expf(-2.0f * ax);
  float r  = (1.0f - t) / (1.0f + t);
  return copysignf(r, x);
}

// --------------------------------------------------------------------------
// Prep: gcnWT[round][k][u]; epWT[round][e][u]; W1aT[k][n]=W1[n][k];
// W1bT[k][n]=W1[n][64+k]. Sizes: 8192 + 640 + 4096 + 4096 = 17024 elements.
__global__ __launch_bounds__(256) void k_prep(
    const float* __restrict__ gcn_W, const float* __restrict__ ep_W,
    const float* __restrict__ W1,
    float* __restrict__ gcnWT, float* __restrict__ epWT,
    float* __restrict__ W1aT, float* __restrict__ W1bT)
{
  int idx = blockIdx.x * 256 + threadIdx.x;
  if (idx < 8192) {                        // gcnWT[r][k][u] = gcn_W[r][u][k]
    int round = idx >> 12, rem = idx & 4095;
    int k = rem >> 6, u = rem & 63;
    gcnWT[idx] = gcn_W[round * 4096 + u * 64 + k];
  } else if (idx < 8832) {                 // epWT[r][e][u] = ep_W[r][u][e]
    int r0 = idx - 8192;
    int round = r0 / 320, rem = r0 % 320;
    int e = rem >> 6, u = rem & 63;
    epWT[r0] = ep_W[round * 320 + u * Ed + e];
  } else if (idx < 12928) {                // W1aT[k][n] = W1[n][k]
    int r0 = idx - 8832;
    int k = r0 >> 6, n = r0 & 63;
    W1aT[r0] = W1[n * 133 + k];
  } else if (idx < 17024) {                // W1bT[k][n] = W1[n][64+k]
    int r0 = idx - 12928;
    int k = r0 >> 6, n = r0 & 63;
    W1bT[r0] = W1[n * 133 + 64 + k];
  }
}

// --------------------------------------------------------------------------
// Fused 2-layer LSTM. 200 blocks x 512 threads, 8 seqs/block.
// Phase t in [0,13]:
//   A waves (tid<256): fused body for t<=12 -- L0 gate dot (stored iff
//     t<12) + xproj off the SAME h0_sh b128 stream (stored iff t>=1).
//   B waves: L1 gates step t-2 (t>=2), a0 seeded from x1_sh[(t-1)&1].
// barrier; L0 update (A, t<12), L1 update (B, t>=2); barrier.
__global__ __launch_bounds__(512) void k_lstm_fused(
    const float* __restrict__ nf,                       // (B,W,N,F)
    const float* __restrict__ Wih0, const float* __restrict__ Whh0,
    const float* __restrict__ bih0, const float* __restrict__ bhh0,
    const float* __restrict__ Wih1, const float* __restrict__ Whh1,
    const float* __restrict__ bih1, const float* __restrict__ bhh1,
    float* __restrict__ hout)                           // (NSEQ, H)
{
  __shared__ float x_sh[SEQPB][WP * Fd];   // 624 (col 12 zeroed)
  __shared__ float wx_sh[NG * Fd];         // 1536: Wih0 rows (row-major)
  __shared__ float h0_sh[SEQPB][Hd];       // 512
  __shared__ float h1_sh[SEQPB][Hd];       // 512
  __shared__ float g0_sh[SEQPB][NG];       // 2048 (post-activation gates L0)
  __shared__ float g1_sh[SEQPB][NG];       // 2048 (post-activation gates L1)
  __shared__ float x1_sh[2][SEQPB][NG];    // 4096 (xv = Wih1.h0 + bias1)

  const int tid  = threadIdx.x;
  const int seq0 = blockIdx.x * SEQPB;
  const int b    = seq0 / Nd;              // uniform (200 % 8 == 0)
  const int n0   = seq0 % Nd;

  for (int idx = tid; idx < SEQPB * WP * Fd; idx += 512) {
    int s = idx / (WP * Fd), r = idx - s * (WP * Fd);
    int t = r / Fd, f = r - t * Fd;
    x_sh[s][r] = (t < Wd) ? nf[((b * Wd + t) * Nd + (n0 + s)) * Fd + f] : 0.f;
  }
  for (int idx = tid; idx < NG * Fd; idx += 512)
    wx_sh[idx] = Wih0[idx];                // linear copy (row-major match)
  ((float*)h0_sh)[tid] = 0.f;              // 512 floats, one per thread
  ((float*)h1_sh)[tid] = 0.f;

  const bool isA = (tid < 256);
  const int j  = tid & 255;                // gate row within this layer
  const int jt = j >> 6;                   // 0=i,1=f,2=g,3=o (wave-uniform)
  const int u  = tid & 63;
  const int w  = (tid >> 6) & 3;           // update ownership: seqs {w, w+4}

  // Per-thread weights: A = Whh0[j] + Wih1[j] (128 wf; Wih0 row via LDS);
  // B = Whh1[j] (64 wf). Plain launch_bounds -> AGPR-backed overflow OK.
  float4 wh[16];                           // Whh0 row j (A) / Whh1 row j (B)
  float4 wi1[16];                          // Wih1 row j (A only)
  float  bias0 = 0.f, bias1 = 0.f;
  if (isA) {
    const float4* wr = (const float4*)(Whh0 + j * Hd);
    #pragma unroll
    for (int q = 0; q < 16; ++q) wh[q] = wr[q];
    const float4* xr = (const float4*)(Wih1 + j * Hd);
    #pragma unroll
    for (int q = 0; q < 16; ++q) wi1[q] = xr[q];
    bias0 = bih0[j] + bhh0[j];
    bias1 = bih1[j] + bhh1[j];
  } else {
    const float4* wr = (const float4*)(Whh1 + j * Hd);
    #pragma unroll
    for (int q = 0; q < 16; ++q) wh[q] = wr[q];
  }

  float cA = 0.f, cB = 0.f;                // cell states for seqs w, w+4
  float hA = 0.f, hB = 0.f;                // B threads: final h1 for w, w+4
  const float* wxp = wx_sh + j * Fd;       // A's Wih0 row (LDS, 2-way = free)
  __syncthreads();

  for (int t = 0; t <= Wd + 1; ++t) {
    // ================= gate section ======================================
    if (isA) {
      if (t <= Wd) {                       // single fused body for t in [0,12]
        #pragma unroll 2
        for (int s = 0; s < SEQPB; ++s) {
          const float* xp = &x_sh[s][t * Fd];        // col 12 = zeros
          float a0 = bias0, a1 = 0.f, a2 = 0.f, a3 = 0.f;
          #pragma unroll
          for (int f = 0; f < Fd; ++f) a1 += xp[f] * wxp[f];
          float xacc = 0.f;
          const float4* h4 = (const float4*)h0_sh[s];
          #pragma unroll
          for (int q = 0; q < 16; ++q) {
            float4 hv = h4[q];                       // ONE b128, two dots
            float d = hv.x * wh[q].x + hv.y * wh[q].y + hv.z * wh[q].z + hv.w * wh[q].w;
            if ((q & 3) == 0) a0 += d; else if ((q & 3) == 1) a1 += d;
            else if ((q & 3) == 2) a2 += d; else a3 += d;
            xacc = fmaf(hv.x, wi1[q].x, xacc);       // xproj for L1 step t-1
            xacc = fmaf(hv.y, wi1[q].y, xacc);
            xacc = fmaf(hv.z, wi1[q].z, xacc);
            xacc = fmaf(hv.w, wi1[q].w, xacc);
          }
          float acc = (a0 + a1) + (a2 + a3);
          if (t < Wd)  g0_sh[s][j] = (jt == 2) ? tanh_fast(acc) : sigm(acc);
          if (t >= 1)  x1_sh[t & 1][s][j] = xacc + bias1;
        }
      }
    } else {
      if (t >= 2) {                        // L1 gates step t-2
        #pragma unroll 2
        for (int s = 0; s < SEQPB; ++s) {
          float a0 = x1_sh[(t - 1) & 1][s][j];   // xv(t-2), written phase t-1
          float a1 = 0.f, a2 = 0.f, a3 = 0.f;
          const float4* h4 = (const float4*)h1_sh[s];
          #pragma unroll
          for (int q = 0; q < 16; ++q) {
            float4 hv = h4[q];
            float d = hv.x * wh[q].x + hv.y * wh[q].y + hv.z * wh[q].z + hv.w * wh[q].w;
            if ((q & 3) == 0) a0 += d; else if ((q & 3) == 1) a1 += d;
            else if ((q & 3) == 2) a2 += d; else a3 += d;
          }
          float acc = (a0 + a1) + (a2 + a3);
          g1_sh[s][j] = (jt == 2) ? tanh_fast(acc) : sigm(acc);
        }
      }
    }
    __syncthreads();                       // gates/xv ready; all h reads done

    // ================= update section (verbatim R9 ownership) ============
    if (isA) {
      if (t < Wd) {                        // L0 update step t
        const float* gb = g0_sh[w];
        float iv = gb[u], fv = gb[64 + u], gv = gb[128 + u], ov = gb[192 + u];
        cA = fv * cA + iv * gv;
        hA = ov * tanh_fast(cA);
        h0_sh[w][u] = hA;
        const float* gb2 = g0_sh[w + 4];
        float iv2 = gb2[u], fv2 = gb2[64 + u], gv2 = gb2[128 + u], ov2 = gb2[192 + u];
        cB = fv2 * cB + iv2 * gv2;
        hB = ov2 * tanh_fast(cB);
        h0_sh[w + 4][u] = hB;
      }
    } else {
      if (t >= 2) {                        // L1 update step t-2
        const float* gb = g1_sh[w];
        float iv = gb[u], fv = gb[64 + u], gv = gb[128 + u], ov = gb[192 + u];
        cA = fv * cA + iv * gv;
        hA = ov * tanh_fast(cA);
        h1_sh[w][u] = hA;
        const float* gb2 = g1_sh[w + 4];
        float iv2 = gb2[u], fv2 = gb2[64 + u], gv2 = gb2[128 + u], ov2 = gb2[192 + u];
        cB = fv2 * cB + iv2 * gv2;
        hB = ov2 * tanh_fast(cB);
        h1_sh[w + 4][u] = hB;
      }
    }
    __syncthreads();                       // h writes visible to next phase
  }

  // Final h1(11) -> hout from B threads' partitioned state. Coalesced.
  if (!isA) {
    hout[(seq0 + w) * Hd + u]     = hA;
    hout[(seq0 + w + 4) * Hd + u] = hB;
  }
}

// --------------------------------------------------------------------------
// Fused per-row node pipeline: wsum -> GCN r0 -> GCN r1 -> u/v precompute.
// One block per row (b,i); 256 threads. adj/ef rows staged into LDS with
// COALESCED loads; all weight reads coalesced via the k_prep transposes.
__global__ __launch_bounds__(256) void k_node(
    const float* __restrict__ ef,    const float* __restrict__ adj,
    const float* __restrict__ h0,
    const float* __restrict__ gcnWT, const float* __restrict__ gcn_b,
    const float* __restrict__ epWT,  const float* __restrict__ ep_b,
    const float* __restrict__ ln_g,  const float* __restrict__ ln_b,
    const float* __restrict__ W1aT,  const float* __restrict__ W1bT,
    const float* __restrict__ b1,
    float* __restrict__ uu, float* __restrict__ vt)
{
  __shared__ float ef_sh[Nd * Ed];   // 1000: edge_last row (coalesced stage)
  __shared__ float adj_sh[Nd];       // 200
  __shared__ float red[4][6];
  __shared__ float w6[6];
  __shared__ float hcur[Hd];

  const int row = blockIdx.x;      // b*200+i
  const int b = row / Nd, i = row % Nd;
  const int tid = threadIdx.x;

  const float* efrow = ef + (size_t)(((b * Wd + (Wd - 1)) * Nd + i)) * (Nd * Ed);
  for (int idx = tid; idx < Nd * Ed; idx += 256) ef_sh[idx] = efrow[idx];
  const float* adjrow = adj + (b * Nd + i) * Nd;
  if (tid < Nd) adj_sh[tid] = adjrow[tid];
  if (tid < Hd) hcur[tid] = h0[row * Hd + tid];
  __syncthreads();

  // ---- wsum: p[e] = sum_j adj*edge[e], p[5] = sum_j adj (order as before)
  float p[6] = {0.f, 0.f, 0.f, 0.f, 0.f, 0.f};
  if (tid < Nd) {
    float a = adj_sh[tid];
    p[5] = a;
    #pragma unroll
    for (int k = 0; k < Ed; ++k) p[k] = a * ef_sh[tid * Ed + k];
  }
  #pragma unroll
  for (int k = 0; k < 6; ++k) {
    float v = p[k];
    for (int off = 32; off > 0; off >>= 1) v += __shfl_down(v, off);
    p[k] = v;
  }
  if ((tid & 63) == 0) {
    #pragma unroll
    for (int k = 0; k < 6; ++k) red[tid >> 6][k] = p[k];
  }
  __syncthreads();
  if (tid < 6)
    w6[tid] = red[0][tid] + red[1][tid] + red[2][tid] + red[3][tid];
  __syncthreads();

  // ---- 2 GCN rounds (wave 0; coalesced transposed-weight reads)
  const int u = tid & 63;
  #pragma unroll
  for (int round = 0; round < 2; ++round) {
    float hnew = 0.f;
    if (tid < 64) {
      const float* gwT = gcnWT + round * 4096;   // [k][u]
      const float* ewT = epWT  + round * 320;    // [e][u]
      float acc = gcn_b[round * Hd + u] + w6[5] * ep_b[round * Hd + u];
      #pragma unroll
      for (int e = 0; e < Ed; ++e) acc += w6[e] * ewT[e * 64 + u];
      #pragma unroll 8
      for (int k = 0; k < Hd; ++k) acc += hcur[k] * gwT[k * 64 + u];

      float mu = acc;
      #pragma unroll
      for (int off = 1; off < 64; off <<= 1) mu += __shfl_xor(mu, off);
      mu *= (1.f / 64.f);
      float d = acc - mu;
      float var = d * d;
      #pragma unroll
      for (int off = 1; off < 64; off <<= 1) var += __shfl_xor(var, off);
      var *= (1.f / 64.f);
      float v = d * rsqrtf(var + LNEPS) * ln_g[round * Hd + u] + ln_b[round * Hd + u];
      hnew = fmaxf(v, 0.f);
    }
    __syncthreads();               // all reads of hcur done
    if (tid < 64) hcur[tid] = hnew;
    __syncthreads();
  }

  // ---- u/v precompute (threads 0..127; coalesced transposed W1 reads)
  if (tid < 64) {
    float acc = b1[tid];
    #pragma unroll 8
    for (int k = 0; k < Hd; ++k) acc += hcur[k] * W1aT[k * 64 + tid];
    uu[row * Hd + tid] = acc;
  } else if (tid < 128) {
    const int n = tid - 64;
    float acc = 0.f;
    #pragma unroll 8
    for (int k = 0; k < Hd; ++k) acc += hcur[k] * W1bT[k * 64 + n];
    vt[n * NSEQ + row] = acc;
  }
}

// --------------------------------------------------------------------------
// Edge MLP: thread per edge. z1[64] lives in VGPRs; W1c/W2/W3/b2 have
// wave-uniform indices -> scalar-pipe loads, fmac v,s,v at VALU issue peak.
__global__ __launch_bounds__(256) void k_mlp(
    const float* __restrict__ ef,
    const float* __restrict__ u, const float* __restrict__ vt,
    const float* __restrict__ W1,
    const float* __restrict__ W2, const float* __restrict__ b2,
    const float* __restrict__ W3, const float* __restrict__ b3,
    float* __restrict__ out)
{
  const int idx = blockIdx.x * 256 + threadIdx.x;   // < 320000
  const int b   = idx / (Nd * Nd);
  const int rem = idx - b * Nd * Nd;
  const int i   = rem / Nd;
  const int jj  = rem - i * Nd;

  const float* e = ef + (((b * Wd + (Wd - 1)) * Nd + i) * Nd + jj) * Ed;
  float e5[Ed];
  #pragma unroll
  for (int q = 0; q < Ed; ++q) e5[q] = e[q];

  const float* ur = u + (b * Nd + i) * Hd;
  const int vcol = b * Nd + jj;

  float z1[64];
  #pragma unroll
  for (int k = 0; k < 64; ++k) {
    float acc = ur[k] + vt[k * NSEQ + vcol];
    const float* w1c = W1 + k * 133 + 128;      // uniform -> scalar loads
    #pragma unroll
    for (int q = 0; q < Ed; ++q) acc += e5[q] * w1c[q];
    z1[k] = fmaxf(acc, 0.f);
  }

  float logit = b3[0];
  #pragma unroll 4
  for (int o = 0; o < 32; ++o) {
    float a0 = b2[o], a1 = 0.f, a2 = 0.f, a3 = 0.f;
    const float* w2 = W2 + o * 64;              // uniform -> scalar loads
    #pragma unroll
    for (int k = 0; k < 64; k += 4) {
      a0 += w2[k]     * z1[k];
      a1 += w2[k + 1] * z1[k + 1];
      a2 += w2[k + 2] * z1[k + 2];
      a3 += w2[k + 3] * z1[k + 3];
    }
    float z2 = fmaxf((a0 + a1) + (a2 + a3), 0.f);
    logit += W3[o] * z2;
  }
  out[idx] = 1.f / (1.f + __expf(-logit));
}

// --------------------------------------------------------------------------
extern "C" void kernel_launch(void* const* d_in, const int* in_sizes, int n_in,
                              void* d_out, int out_size, void* d_ws, size_t ws_size,
                              hipStream_t stream) {
  (void)in_sizes; (void)n_in; (void)out_size; (void)ws_size;
  const float* nf   = (const float*)d_in[0];
  const float* ef   = (const float*)d_in[1];
  const float* adj  = (const float*)d_in[2];
  const float* Wih0 = (const float*)d_in[3];
  const float* Whh0 = (const float*)d_in[4];
  const float* bih0 = (const float*)d_in[5];
  const float* bhh0 = (const float*)d_in[6];
  const float* Wih1 = (const float*)d_in[7];
  const float* Whh1 = (const float*)d_in[8];
  const float* bih1 = (const float*)d_in[9];
  const float* bhh1 = (const float*)d_in[10];
  const float* gcnW = (const float*)d_in[11];
  const float* gcnB = (const float*)d_in[12];
  const float* epW  = (const float*)d_in[13];
  const float* epB  = (const float*)d_in[14];
  const float* lnG  = (const float*)d_in[15];
  const float* lnB  = (const float*)d_in[16];
  const float* W1   = (const float*)d_in[17];
  const float* b1   = (const float*)d_in[18];
  const float* W2   = (const float*)d_in[19];
  const float* b2   = (const float*)d_in[20];
  const float* W3   = (const float*)d_in[21];
  const float* b3   = (const float*)d_in[22];
  float* out = (float*)d_out;

  // Workspace layout (floats).
  float* ws   = (float*)d_ws;
  float* h0   = ws;                        // 102,400
  float* uu   = h0   + 102400;             // 102,400
  float* vt   = uu   + 102400;             // 102,400
  float* gWT  = vt   + 102400;             // 8,192
  float* eWT  = gWT  + 8192;               // 640
  float* W1aT = eWT  + 640;                // 4,096
  float* W1bT = W1aT + 4096;               // 4,096

  k_prep      <<<67,        256, 0, stream>>>(gcnW, epW, W1, gWT, eWT, W1aT, W1bT);
  k_lstm_fused<<<NSEQ/SEQPB,512, 0, stream>>>(nf, Wih0, Whh0, bih0, bhh0,
                                              Wih1, Whh1, bih1, bhh1, h0);
  k_node      <<<1600,      256, 0, stream>>>(ef, adj, h0, gWT, gcnB, eWT, epB,
                                              lnG, lnB, W1aT, W1bT, b1, uu, vt);
  k_mlp       <<<1250,      256, 0, stream>>>(ef, uu, vt, W1, W2, b2, W3, b3, out);
}